// Round 2
// baseline (479.066 us; speedup 1.0000x reference)
//
#include <hip/hip_runtime.h>
#include <math.h>

#define Q_NODES 100000
#define S_NODES 100000
#define N_EDGES 3200000
#define HIDDEN 64
#define OUT_DIM 128

// ---------- bucket partition parameters ----------
#define QPB   128                    // queries per bucket (bucket = q >> 7)
#define NB    782                    // ceil(Q_NODES / QPB)
#define CAPB  4608                   // bucket capacity: mean 4096, +8 sigma
#define TILE  4096                   // edges per partition block
#define NT4   (N_EDGES / 4)          // int4 count per edge row
#define CSTR  16                     // cursor stride (ints) -> one 64B line per bucket

// ---------- FAST-PATH workspace layout (bytes) ----------
#define F_CURSOR_OFF 0               // 782 * 64 B (padded: 1 cacheline per bucket)
#define F_DONE_OFF   50048
#define F_NORM_OFF   50112
#define F_PSUM_OFF   50240
#define F_PSUMSQ_OFF 78400
#define F_FEATS_OFF  106560
#define F_SP4_OFF    3706560
#define F_SLOTS_OFF  5306560
#define F_ZERO_BYTES 50052           // cursor + done counter
#define F_WS_NEED    (5306560ull + (unsigned long long)(NB * CAPB + 1) * 4)

// ---------- FALLBACK workspace layout (round-1 algorithm) ----------
#define B_ACC_OFF    0
#define B_STATS_OFF  4800000
#define B_NORM_OFF   4800144
#define B_FEATS_OFF  4800224
#define B_ZERO_BYTES 4800144

__device__ __forceinline__ void atomAddF(float* p, float v) {
#if defined(__gfx950__) || defined(__gfx942__) || defined(__gfx90a__)
    unsafeAtomicAdd(p, v);
#else
    atomicAdd(p, v);
#endif
}

// ============================================================================
// Shared device helpers
// ============================================================================

__device__ __forceinline__ void eig3_sym(
        float a00, float a01, float a02, float a11, float a12, float a22,
        float& e1, float& e2, float& e3) {
    float p1 = a01 * a01 + a02 * a02 + a12 * a12;
    float qm = (a00 + a11 + a22) * (1.0f / 3.0f);
    float b00 = a00 - qm, b11 = a11 - qm, b22 = a22 - qm;
    float p2 = b00 * b00 + b11 * b11 + b22 * b22 + 2.0f * p1;
    if (p2 <= 1e-24f) {
        e1 = qm; e2 = qm; e3 = qm;
    } else {
        float p = sqrtf(p2 * (1.0f / 6.0f));
        float invp = 1.0f / p;
        float c00 = b00 * invp, c11 = b11 * invp, c22 = b22 * invp;
        float c01 = a01 * invp, c02 = a02 * invp, c12 = a12 * invp;
        float detB = c00 * (c11 * c22 - c12 * c12)
                   - c01 * (c01 * c22 - c12 * c02)
                   + c02 * (c01 * c12 - c11 * c02);
        float r = 0.5f * detB;
        r = fminf(fmaxf(r, -1.0f), 1.0f);
        float phi = acosf(r) * (1.0f / 3.0f);
        e1 = qm + 2.0f * p * cosf(phi);
        e3 = qm + 2.0f * p * cosf(phi + 2.0943951023931953f); // +2pi/3
        e2 = 3.0f * qm - e1 - e3;
    }
}

// sums: n,sumd,sumd2,sx,sy,sz,xx,xy,xz,yy,yz,zz -> 9 features
__device__ __forceinline__ void sums_to_feats(
        const float* s, float qx, float qy, float qz, float* f) {
    float n = s[0];
#pragma unroll
    for (int k = 0; k < 9; ++k) f[k] = 0.0f;
    if (n > 0.0f) {
        float inv = 1.0f / n;
        float Davg = s[1] * inv;
        float Dvar = fmaxf(s[2] * inv - Davg * Davg, 0.0f);
        float cx = s[3] * inv, cy = s[4] * inv, cz = s[5] * inv;
        float a00 = fmaxf(s[6] * inv - cx * cx, 0.0f);
        float a01 = s[7] * inv - cx * cy;
        float a02 = s[8] * inv - cx * cz;
        float a11 = fmaxf(s[9] * inv - cy * cy, 0.0f);
        float a12 = s[10] * inv - cy * cz;
        float a22 = fmaxf(s[11] * inv - cz * cz, 0.0f);
        float e1, e2, e3;
        eig3_sym(a00, a01, a02, a11, a12, a22, e1, e2, e3);
        f[0] = n; f[1] = Davg; f[2] = Dvar;
        f[3] = cx - qx; f[4] = cy - qy; f[5] = cz - qz;
        f[6] = e1; f[7] = e2; f[8] = e3;
    }
}

// ============================================================================
// FAST PATH
// ============================================================================

__global__ __launch_bounds__(512, 4) void partition_kernel(
        const int* __restrict__ edge,
        const float* __restrict__ sp,
        float4* __restrict__ sp4,
        int* __restrict__ cursor,
        unsigned int* __restrict__ slots) {
    __shared__ unsigned int s_rec[TILE];   // 16 KB: packed records, bucket-sorted
    __shared__ int s_posh[TILE];           // 16 KB: phase A = histogram[NB]; phase B = dest idx
    __shared__ int s_cur[NB];
    __shared__ int s_off[NB];
    __shared__ int s_wsum[8];

    int tid = threadIdx.x;
    int lane = tid & 63, wv = tid >> 6;
    int tileStart = blockIdx.x * TILE;
    int tileCount = N_EDGES - tileStart;
    if (tileCount > TILE) tileCount = TILE;

    // fused sp -> sp4 pad
    {
        int i = blockIdx.x * 512 + tid;
        if (i < S_NODES)
            sp4[i] = make_float4(sp[3 * i], sp[3 * i + 1], sp[3 * i + 2], 0.0f);
    }

    for (int b = tid; b < NB; b += 512) s_posh[b] = 0;
    __syncthreads();

    const int4* eq4 = (const int4*)edge;
    const int4* es4 = (const int4*)(edge + N_EDGES);
    int base4 = blockIdx.x * (TILE / 4);
    int4 q4[2], s4[2];
    bool v[2];
#pragma unroll
    for (int j = 0; j < 2; ++j) {
        int i4 = base4 + tid + j * 512;
        v[j] = i4 < NT4;
        int ic = v[j] ? i4 : 0;
        q4[j] = eq4[ic];
        s4[j] = es4[ic];
        if (v[j]) {
            atomicAdd(&s_posh[q4[j].x >> 7], 1);
            atomicAdd(&s_posh[q4[j].y >> 7], 1);
            atomicAdd(&s_posh[q4[j].z >> 7], 1);
            atomicAdd(&s_posh[q4[j].w >> 7], 1);
        }
    }
    __syncthreads();

    // exclusive prefix of histogram -> s_cur
    int local[4], tsum = 0;
#pragma unroll
    for (int j = 0; j < 4; ++j) {
        int idx = 4 * tid + j;
        local[j] = (idx < NB) ? s_posh[idx] : 0;
        tsum += local[j];
    }
    int inc = tsum;
#pragma unroll
    for (int off = 1; off < 64; off <<= 1) {
        int t = __shfl_up(inc, off);
        if (lane >= off) inc += t;
    }
    if (lane == 63) s_wsum[wv] = inc;
    __syncthreads();
    int wbase = 0;
    for (int w = 0; w < wv; ++w) wbase += s_wsum[w];
    int run = wbase + inc - tsum;
#pragma unroll
    for (int j = 0; j < 4; ++j) {
        int idx = 4 * tid + j;
        if (idx < NB) s_cur[idx] = run;
        run += local[j];
    }
    __syncthreads();

    // reserve global space per non-empty bucket (padded cursor: 1 line/bucket)
    for (int b = tid; b < NB; b += 512) {
        int c = s_posh[b];
        int base = c ? atomicAdd(&cursor[b * CSTR], c) : 0;
        s_off[b] = b * CAPB + base - s_cur[b];
    }
    __syncthreads();   // histogram region of s_posh is now dead

    // scatter into bucket-sorted LDS stage, computing global dest on the fly
#pragma unroll
    for (int j = 0; j < 2; ++j) {
        if (v[j]) {
            int qs[4] = { q4[j].x, q4[j].y, q4[j].z, q4[j].w };
            int ss[4] = { s4[j].x, s4[j].y, s4[j].z, s4[j].w };
#pragma unroll
            for (int m = 0; m < 4; ++m) {
                int bkt = qs[m] >> 7;
                int idx = atomicAdd(&s_cur[bkt], 1);
                int gpos = idx + s_off[bkt];
                if (gpos >= (bkt + 1) * CAPB) gpos = NB * CAPB;  // overflow guard
                s_rec[idx] = ((unsigned)(qs[m] & (QPB - 1)) << 17) | (unsigned)ss[m];
                s_posh[idx] = gpos;
            }
        }
    }
    __syncthreads();

    // write-out: bucket-contiguous runs -> mostly coalesced
    for (int i = tid; i < tileCount; i += 512)
        slots[s_posh[i]] = s_rec[i];
}

// Direct LDS-atomic accumulate (no sort), 4 wave-replicated partial tables.
// Dataset stats fused via fence + done-counter; last block computes norm.
__global__ __launch_bounds__(512, 4) void bucket_kernel(
        const int* __restrict__ cursor,
        const unsigned int* __restrict__ slots,
        const float4* __restrict__ sp4,
        const float* __restrict__ qp,
        float* __restrict__ feats,
        float* __restrict__ psum,
        float* __restrict__ psumsq,
        int* __restrict__ done,
        float* __restrict__ norm) {
    __shared__ float qtile[QPB * 3];
    __shared__ float s_part[4][QPB][13];      // 26 KB: 12 sums + pad (13 coprime 32)
    __shared__ float s_red1[8][9], s_red2[8][9];
    __shared__ int s_last;

    int tid = threadIdx.x;
    int b = blockIdx.x;
    int cnt = cursor[b * CSTR];
    if (cnt > CAPB) cnt = CAPB;

    for (int i = tid; i < QPB * 3; i += 512) {
        int g = b * QPB * 3 + i;
        qtile[i] = (g < Q_NODES * 3) ? qp[g] : 0.0f;
    }
    {
        float* z = &s_part[0][0][0];
        for (int i = tid; i < 4 * QPB * 13; i += 512) z[i] = 0.0f;
    }
    __syncthreads();

    const unsigned int* bslots = slots + b * CAPB;
    int lane = tid & 63, wv = tid >> 6;
    float* rep = &s_part[wv & 3][0][0];
    for (int i = tid; i < cnt; i += 512) {
        unsigned rec = bslots[i];
        int q = rec >> 17;
        float4 sv = sp4[rec & 0x1FFFF];
        float qx = qtile[3 * q + 0], qy = qtile[3 * q + 1], qz = qtile[3 * q + 2];
        float dx = sv.x - qx, dy = sv.y - qy, dz = sv.z - qz;
        float d2 = dx * dx + dy * dy + dz * dz;
        float* pr = rep + q * 13;
        atomicAdd(pr + 0, 1.0f);
        atomicAdd(pr + 1, sqrtf(d2));
        atomicAdd(pr + 2, d2);
        atomicAdd(pr + 3, sv.x);
        atomicAdd(pr + 4, sv.y);
        atomicAdd(pr + 5, sv.z);
        atomicAdd(pr + 6, sv.x * sv.x);
        atomicAdd(pr + 7, sv.x * sv.y);
        atomicAdd(pr + 8, sv.x * sv.z);
        atomicAdd(pr + 9, sv.y * sv.y);
        atomicAdd(pr + 10, sv.y * sv.z);
        atomicAdd(pr + 11, sv.z * sv.z);
    }
    __syncthreads();

    // per-query finalize by threads 0..127
    float f[9];
#pragma unroll
    for (int k = 0; k < 9; ++k) f[k] = 0.0f;
    int q = b * QPB + (tid & (QPB - 1));
    if (tid < QPB && q < Q_NODES) {
        float qx = qtile[3 * tid + 0], qy = qtile[3 * tid + 1], qz = qtile[3 * tid + 2];
        float s[12];
#pragma unroll
        for (int k = 0; k < 12; ++k)
            s[k] = ((s_part[0][tid][k] + s_part[1][tid][k])
                  + (s_part[2][tid][k] + s_part[3][tid][k]));
        sums_to_feats(s, qx, qy, qz, f);
#pragma unroll
        for (int k = 0; k < 9; ++k) feats[k * Q_NODES + q] = f[k];  // coalesced per k
    }

    // dataset-wide stats: wave reduce -> LDS -> one partial row per block
#pragma unroll
    for (int k = 0; k < 9; ++k) {
        float s1 = f[k];
        float s2 = f[k] * f[k];
#pragma unroll
        for (int off = 32; off > 0; off >>= 1) {
            s1 += __shfl_down(s1, off);
            s2 += __shfl_down(s2, off);
        }
        if (lane == 0) { s_red1[wv][k] = s1; s_red2[wv][k] = s2; }
    }
    __syncthreads();
    if (tid < 9) {
        float t1 = 0.0f, t2 = 0.0f;
#pragma unroll
        for (int w = 0; w < 8; ++w) { t1 += s_red1[w][tid]; t2 += s_red2[w][tid]; }
        psum[tid * NB + b]   = t1;
        psumsq[tid * NB + b] = t2;
    }
    __threadfence();                 // release partial rows device-wide
    __syncthreads();
    if (tid == 0) s_last = (atomicAdd(done, 1) == NB - 1);
    __syncthreads();
    if (s_last) {
        __threadfence();             // acquire other blocks' rows
        int k = tid >> 5, l32 = tid & 31;
        if (k < 9) {
            double a1 = 0.0, a2 = 0.0;
            for (int bb = l32; bb < NB; bb += 32) {
                a1 += (double)psum[k * NB + bb];
                a2 += (double)psumsq[k * NB + bb];
            }
#pragma unroll
            for (int off = 16; off > 0; off >>= 1) {
                a1 += __shfl_down(a1, off);
                a2 += __shfl_down(a2, off);
            }
            if (l32 == 0) {
                double S = a1, S2 = a2;
                double mean = S / (double)Q_NODES;
                double var = (S2 - S * S / (double)Q_NODES) / (double)(Q_NODES - 1);
                if (var < 0.0) var = 0.0;
                double sd = sqrt(var);
                if (sd < 1e-6) sd = 1.0;
                norm[k] = (float)mean;
                norm[9 + k] = (float)(1.0 / sd);
            }
        }
    }
}

// ============================================================================
// MLP: 512 threads, single pass over all 128 outputs. 73 KB LDS -> 2 blocks/CU
// (16 waves/CU). Raw feats staged to LDS early (coalesced), W2^T via float4.
// ============================================================================

__global__ __launch_bounds__(512, 2) void mlp_kernel(
        const float* __restrict__ feats,
        const float* __restrict__ norm,
        const float* __restrict__ W1, const float* __restrict__ b1,
        const float* __restrict__ W2, const float* __restrict__ b2,
        float* __restrict__ out) {
    __shared__ float sW1[576];        // [64][9]
    __shared__ float sB1[64];
    __shared__ float sB2[128];
    __shared__ float sNorm[18];
    __shared__ float sfeat[9 * 128];  // raw feats [k][q]
    __shared__ float w2t[64 * 128];   // [k][o]
    __shared__ float ht[64 * 128];    // [k][q]

    int tid = threadIdx.x;
    int blk_q = blockIdx.x;

    // issue feats loads first: coalesced, latency hides under weight staging
    for (int i = tid; i < 9 * 128; i += 512) {
        int k = i >> 7, qq = i & 127;
        int qg = blk_q * 128 + qq;
        if (qg >= Q_NODES) qg = Q_NODES - 1;
        sfeat[i] = feats[k * Q_NODES + qg];
    }

    // W2^T staging: thread owns column o = tid&127, 16 k's via 4 float4 loads
    {
        int o = tid & 127, kb = (tid >> 7) * 16;
        const float4* w2v = (const float4*)(W2 + o * 64 + kb);
#pragma unroll
        for (int j = 0; j < 4; ++j) {
            float4 w = w2v[j];
            int k = kb + j * 4;
            w2t[(k + 0) * 128 + o] = w.x;
            w2t[(k + 1) * 128 + o] = w.y;
            w2t[(k + 2) * 128 + o] = w.z;
            w2t[(k + 3) * 128 + o] = w.w;
        }
    }
    for (int i = tid; i < 576; i += 512) sW1[i] = W1[i];
    if (tid < 64) sB1[tid] = b1[tid];
    if (tid < 128) sB2[tid] = b2[tid];
    if (tid < 18) sNorm[tid] = norm[tid];
    __syncthreads();

    // Layer 1: q = tid&127, quarter = tid>>7 -> 16 h-rows each
    {
        int qq = tid & 127, quarter = tid >> 7;
        float f[9];
#pragma unroll
        for (int k = 0; k < 9; ++k)
            f[k] = (sfeat[k * 128 + qq] - sNorm[k]) * sNorm[9 + k];
#pragma unroll 4
        for (int j = 0; j < 16; ++j) {
            int ko = quarter * 16 + j;
            float a = sB1[ko];
#pragma unroll
            for (int kf = 0; kf < 9; ++kf) a = fmaf(f[kf], sW1[ko * 9 + kf], a);
            ht[ko * 128 + qq] = fmaxf(a, 0.0f);   // lanes span q -> conflict-free
        }
    }
    __syncthreads();

    // Layer 2: thread tile 8q x 4o; qt in [0,16), ot in [0,32)
    int qt = tid >> 5, ot = tid & 31;
    int q0 = qt * 8, o0 = ot * 4;
    float acc[8][4];
#pragma unroll
    for (int i = 0; i < 8; ++i)
#pragma unroll
        for (int j = 0; j < 4; ++j) acc[i][j] = 0.0f;

#pragma unroll 4
    for (int k = 0; k < 64; ++k) {
        float4 h0 = *(const float4*)&ht[k * 128 + q0];       // 2-addr broadcast
        float4 h1 = *(const float4*)&ht[k * 128 + q0 + 4];
        float4 w  = *(const float4*)&w2t[k * 128 + o0];      // 4-way, cheap
        float hh[8] = { h0.x, h0.y, h0.z, h0.w, h1.x, h1.y, h1.z, h1.w };
#pragma unroll
        for (int i = 0; i < 8; ++i) {
            acc[i][0] = fmaf(hh[i], w.x, acc[i][0]);
            acc[i][1] = fmaf(hh[i], w.y, acc[i][1]);
            acc[i][2] = fmaf(hh[i], w.z, acc[i][2]);
            acc[i][3] = fmaf(hh[i], w.w, acc[i][3]);
        }
    }

    float4 bb = *(const float4*)&sB2[o0];
#pragma unroll
    for (int i = 0; i < 8; ++i) {
        int qg = blk_q * 128 + q0 + i;
        if (qg < Q_NODES) {
            float4 vv = make_float4(acc[i][0] + bb.x, acc[i][1] + bb.y,
                                    acc[i][2] + bb.z, acc[i][3] + bb.w);
            *(float4*)(out + (size_t)qg * 128 + o0) = vv;
        }
    }
}

// ============================================================================
// FALLBACK PATH (round-1 algorithm, used only if ws_size too small)
// ============================================================================

__global__ __launch_bounds__(256) void edge_kernel(
        const int* __restrict__ edge,
        const float* __restrict__ sp,
        const float* __restrict__ qp,
        float* __restrict__ acc) {
    int e = blockIdx.x * 256 + threadIdx.x;
    if (e >= N_EDGES) return;
    int q = edge[e];
    int s = edge[N_EDGES + e];
    float sx = sp[3 * s + 0], sy = sp[3 * s + 1], sz = sp[3 * s + 2];
    float qx = qp[3 * q + 0], qy = qp[3 * q + 1], qz = qp[3 * q + 2];
    float dx = sx - qx, dy = sy - qy, dz = sz - qz;
    float d2 = dx * dx + dy * dy + dz * dz;
    atomAddF(acc + 0 * Q_NODES + q, 1.0f);
    atomAddF(acc + 1 * Q_NODES + q, sqrtf(d2));
    atomAddF(acc + 2 * Q_NODES + q, d2);
    atomAddF(acc + 3 * Q_NODES + q, sx);
    atomAddF(acc + 4 * Q_NODES + q, sy);
    atomAddF(acc + 5 * Q_NODES + q, sz);
    atomAddF(acc + 6 * Q_NODES + q, sx * sx);
    atomAddF(acc + 7 * Q_NODES + q, sx * sy);
    atomAddF(acc + 8 * Q_NODES + q, sx * sz);
    atomAddF(acc + 9 * Q_NODES + q, sy * sy);
    atomAddF(acc + 10 * Q_NODES + q, sy * sz);
    atomAddF(acc + 11 * Q_NODES + q, sz * sz);
}

__global__ __launch_bounds__(256) void finalize_kernel(
        const float* __restrict__ acc,
        const float* __restrict__ qp,
        float* __restrict__ feats,
        double* __restrict__ stats) {
    int q = blockIdx.x * 256 + threadIdx.x;
    float f[9];
#pragma unroll
    for (int k = 0; k < 9; ++k) f[k] = 0.0f;
    if (q < Q_NODES) {
        float s[12];
#pragma unroll
        for (int k = 0; k < 12; ++k) s[k] = acc[k * Q_NODES + q];
        float qx = qp[3 * q + 0], qy = qp[3 * q + 1], qz = qp[3 * q + 2];
        sums_to_feats(s, qx, qy, qz, f);
#pragma unroll
        for (int k = 0; k < 9; ++k) feats[k * Q_NODES + q] = f[k];
    }
    int lane = threadIdx.x & 63;
#pragma unroll
    for (int k = 0; k < 9; ++k) {
        float s1 = f[k];
        float s2 = f[k] * f[k];
#pragma unroll
        for (int off = 32; off > 0; off >>= 1) {
            s1 += __shfl_down(s1, off);
            s2 += __shfl_down(s2, off);
        }
        if (lane == 0) {
            atomicAdd(&stats[k], (double)s1);
            atomicAdd(&stats[9 + k], (double)s2);
        }
    }
}

__global__ void stats_kernel(const double* __restrict__ stats,
                             float* __restrict__ norm) {
    int k = threadIdx.x;
    if (k < 9) {
        double S = stats[k], S2 = stats[9 + k];
        double mean = S / (double)Q_NODES;
        double var = (S2 - S * S / (double)Q_NODES) / (double)(Q_NODES - 1);
        if (var < 0.0) var = 0.0;
        double sd = sqrt(var);
        if (sd < 1e-6) sd = 1.0;
        norm[k] = (float)mean;
        norm[9 + k] = (float)(1.0 / sd);
    }
}

// ============================================================================

extern "C" void kernel_launch(void* const* d_in, const int* in_sizes, int n_in,
                              void* d_out, int out_size, void* d_ws, size_t ws_size,
                              hipStream_t stream) {
    const float* sp   = (const float*)d_in[0];
    const float* qp   = (const float*)d_in[1];
    const int*   edge = (const int*)d_in[2];
    const float* W1   = (const float*)d_in[3];
    const float* b1   = (const float*)d_in[4];
    const float* W2   = (const float*)d_in[5];
    const float* b2   = (const float*)d_in[6];
    float* out = (float*)d_out;
    char* ws = (char*)d_ws;

    if (ws_size >= F_WS_NEED) {
        int*          cursor = (int*)(ws + F_CURSOR_OFF);
        int*          done   = (int*)(ws + F_DONE_OFF);
        float*        norm   = (float*)(ws + F_NORM_OFF);
        float*        psum   = (float*)(ws + F_PSUM_OFF);
        float*        psumsq = (float*)(ws + F_PSUMSQ_OFF);
        float*        feats  = (float*)(ws + F_FEATS_OFF);
        float4*       sp4    = (float4*)(ws + F_SP4_OFF);
        unsigned int* slots  = (unsigned int*)(ws + F_SLOTS_OFF);

        hipMemsetAsync(ws, 0, F_ZERO_BYTES, stream);
        partition_kernel<<<(N_EDGES + TILE - 1) / TILE, 512, 0, stream>>>(
            edge, sp, sp4, cursor, slots);
        bucket_kernel<<<NB, 512, 0, stream>>>(
            cursor, slots, sp4, qp, feats, psum, psumsq, done, norm);
        mlp_kernel<<<NB, 512, 0, stream>>>(feats, norm, W1, b1, W2, b2, out);
    } else {
        float*  acc   = (float*)(ws + B_ACC_OFF);
        double* stats = (double*)(ws + B_STATS_OFF);
        float*  norm  = (float*)(ws + B_NORM_OFF);
        float*  feats = (float*)(ws + B_FEATS_OFF);

        hipMemsetAsync(ws, 0, B_ZERO_BYTES, stream);
        edge_kernel<<<N_EDGES / 256, 256, 0, stream>>>(edge, sp, qp, acc);
        finalize_kernel<<<(Q_NODES + 255) / 256, 256, 0, stream>>>(acc, qp, feats, stats);
        stats_kernel<<<1, 64, 0, stream>>>(stats, norm);
        mlp_kernel<<<NB, 512, 0, stream>>>(feats, norm, W1, b1, W2, b2, out);
    }
}

// Round 3
// 313.876 us; speedup vs baseline: 1.5263x; 1.5263x over previous
//
#include <hip/hip_runtime.h>
#include <math.h>

#define Q_NODES 100000
#define S_NODES 100000
#define N_EDGES 3200000
#define HIDDEN 64
#define OUT_DIM 128

// ---------- bucket partition parameters ----------
#define QPB   128                    // queries per bucket (bucket = q >> 7)
#define NB    782                    // ceil(Q_NODES / QPB)
#define CAPB  4608                   // bucket capacity: mean 4096, +8 sigma
#define TILE  4096                   // edges per partition block
#define NT4   (N_EDGES / 4)          // int4 count per edge row
#define CSTR  16                     // cursor stride (ints) -> one 64B line per bucket

// ---------- FAST-PATH workspace layout (bytes) ----------
#define F_CURSOR_OFF 0               // 782 * 64 B (padded: 1 cacheline per bucket)
#define F_DONE_OFF   50048
#define F_NORM_OFF   50112
#define F_PSUM_OFF   50240
#define F_PSUMSQ_OFF 78400
#define F_FEATS_OFF  106560
#define F_SP4_OFF    3706560
#define F_SLOTS_OFF  5306560
#define F_ZERO_BYTES 50052           // cursor + done counter
#define F_WS_NEED    (5306560ull + (unsigned long long)(NB * CAPB + 1) * 4)

// ---------- FALLBACK workspace layout (round-1 algorithm) ----------
#define B_ACC_OFF    0
#define B_STATS_OFF  4800000
#define B_NORM_OFF   4800144
#define B_FEATS_OFF  4800224
#define B_ZERO_BYTES 4800144

__device__ __forceinline__ void atomAddF(float* p, float v) {
#if defined(__gfx950__) || defined(__gfx942__) || defined(__gfx90a__)
    unsafeAtomicAdd(p, v);
#else
    atomicAdd(p, v);
#endif
}

// ============================================================================
// Shared device helpers
// ============================================================================

__device__ __forceinline__ void eig3_sym(
        float a00, float a01, float a02, float a11, float a12, float a22,
        float& e1, float& e2, float& e3) {
    float p1 = a01 * a01 + a02 * a02 + a12 * a12;
    float qm = (a00 + a11 + a22) * (1.0f / 3.0f);
    float b00 = a00 - qm, b11 = a11 - qm, b22 = a22 - qm;
    float p2 = b00 * b00 + b11 * b11 + b22 * b22 + 2.0f * p1;
    if (p2 <= 1e-24f) {
        e1 = qm; e2 = qm; e3 = qm;
    } else {
        float p = sqrtf(p2 * (1.0f / 6.0f));
        float invp = 1.0f / p;
        float c00 = b00 * invp, c11 = b11 * invp, c22 = b22 * invp;
        float c01 = a01 * invp, c02 = a02 * invp, c12 = a12 * invp;
        float detB = c00 * (c11 * c22 - c12 * c12)
                   - c01 * (c01 * c22 - c12 * c02)
                   + c02 * (c01 * c12 - c11 * c02);
        float r = 0.5f * detB;
        r = fminf(fmaxf(r, -1.0f), 1.0f);
        float phi = acosf(r) * (1.0f / 3.0f);
        e1 = qm + 2.0f * p * cosf(phi);
        e3 = qm + 2.0f * p * cosf(phi + 2.0943951023931953f); // +2pi/3
        e2 = 3.0f * qm - e1 - e3;
    }
}

// sums: n,sumd,sumd2,sx,sy,sz,xx,xy,xz,yy,yz,zz -> 9 features
__device__ __forceinline__ void sums_to_feats(
        const float* s, float qx, float qy, float qz, float* f) {
    float n = s[0];
#pragma unroll
    for (int k = 0; k < 9; ++k) f[k] = 0.0f;
    if (n > 0.0f) {
        float inv = 1.0f / n;
        float Davg = s[1] * inv;
        float Dvar = fmaxf(s[2] * inv - Davg * Davg, 0.0f);
        float cx = s[3] * inv, cy = s[4] * inv, cz = s[5] * inv;
        float a00 = fmaxf(s[6] * inv - cx * cx, 0.0f);
        float a01 = s[7] * inv - cx * cy;
        float a02 = s[8] * inv - cx * cz;
        float a11 = fmaxf(s[9] * inv - cy * cy, 0.0f);
        float a12 = s[10] * inv - cy * cz;
        float a22 = fmaxf(s[11] * inv - cz * cz, 0.0f);
        float e1, e2, e3;
        eig3_sym(a00, a01, a02, a11, a12, a22, e1, e2, e3);
        f[0] = n; f[1] = Davg; f[2] = Dvar;
        f[3] = cx - qx; f[4] = cy - qy; f[5] = cz - qz;
        f[6] = e1; f[7] = e2; f[8] = e3;
    }
}

// ============================================================================
// FAST PATH
// ============================================================================

__global__ __launch_bounds__(512, 4) void partition_kernel(
        const int* __restrict__ edge,
        const float* __restrict__ sp,
        float4* __restrict__ sp4,
        int* __restrict__ cursor,
        unsigned int* __restrict__ slots) {
    __shared__ unsigned int s_rec[TILE];   // 16 KB: packed records, bucket-sorted
    __shared__ int s_posh[TILE];           // 16 KB: phase A = histogram[NB]; phase B = dest idx
    __shared__ int s_cur[NB];
    __shared__ int s_off[NB];
    __shared__ int s_wsum[8];

    int tid = threadIdx.x;
    int lane = tid & 63, wv = tid >> 6;
    int tileStart = blockIdx.x * TILE;
    int tileCount = N_EDGES - tileStart;
    if (tileCount > TILE) tileCount = TILE;

    // fused sp -> sp4 pad
    {
        int i = blockIdx.x * 512 + tid;
        if (i < S_NODES)
            sp4[i] = make_float4(sp[3 * i], sp[3 * i + 1], sp[3 * i + 2], 0.0f);
    }

    for (int b = tid; b < NB; b += 512) s_posh[b] = 0;
    __syncthreads();

    const int4* eq4 = (const int4*)edge;
    const int4* es4 = (const int4*)(edge + N_EDGES);
    int base4 = blockIdx.x * (TILE / 4);
    int4 q4[2], s4[2];
    bool v[2];
#pragma unroll
    for (int j = 0; j < 2; ++j) {
        int i4 = base4 + tid + j * 512;
        v[j] = i4 < NT4;
        int ic = v[j] ? i4 : 0;
        q4[j] = eq4[ic];
        s4[j] = es4[ic];
        if (v[j]) {
            atomicAdd(&s_posh[q4[j].x >> 7], 1);
            atomicAdd(&s_posh[q4[j].y >> 7], 1);
            atomicAdd(&s_posh[q4[j].z >> 7], 1);
            atomicAdd(&s_posh[q4[j].w >> 7], 1);
        }
    }
    __syncthreads();

    // exclusive prefix of histogram -> s_cur
    int local[4], tsum = 0;
#pragma unroll
    for (int j = 0; j < 4; ++j) {
        int idx = 4 * tid + j;
        local[j] = (idx < NB) ? s_posh[idx] : 0;
        tsum += local[j];
    }
    int inc = tsum;
#pragma unroll
    for (int off = 1; off < 64; off <<= 1) {
        int t = __shfl_up(inc, off);
        if (lane >= off) inc += t;
    }
    if (lane == 63) s_wsum[wv] = inc;
    __syncthreads();
    int wbase = 0;
    for (int w = 0; w < wv; ++w) wbase += s_wsum[w];
    int run = wbase + inc - tsum;
#pragma unroll
    for (int j = 0; j < 4; ++j) {
        int idx = 4 * tid + j;
        if (idx < NB) s_cur[idx] = run;
        run += local[j];
    }
    __syncthreads();

    // reserve global space per non-empty bucket (padded cursor: 1 line/bucket)
    for (int b = tid; b < NB; b += 512) {
        int c = s_posh[b];
        int base = c ? atomicAdd(&cursor[b * CSTR], c) : 0;
        s_off[b] = b * CAPB + base - s_cur[b];
    }
    __syncthreads();   // histogram region of s_posh is now dead

    // scatter into bucket-sorted LDS stage, computing global dest on the fly
#pragma unroll
    for (int j = 0; j < 2; ++j) {
        if (v[j]) {
            int qs[4] = { q4[j].x, q4[j].y, q4[j].z, q4[j].w };
            int ss[4] = { s4[j].x, s4[j].y, s4[j].z, s4[j].w };
#pragma unroll
            for (int m = 0; m < 4; ++m) {
                int bkt = qs[m] >> 7;
                int idx = atomicAdd(&s_cur[bkt], 1);
                int gpos = idx + s_off[bkt];
                if (gpos >= (bkt + 1) * CAPB) gpos = NB * CAPB;  // overflow guard
                s_rec[idx] = ((unsigned)(qs[m] & (QPB - 1)) << 17) | (unsigned)ss[m];
                s_posh[idx] = gpos;
            }
        }
    }
    __syncthreads();

    // write-out: bucket-contiguous runs -> mostly coalesced
    for (int i = tid; i < tileCount; i += 512)
        slots[s_posh[i]] = s_rec[i];
}

// Sort-based accumulate (round-1 proven): LDS counting sort, then 4 threads
// per query over contiguous runs, register sums, deterministic combine.
// Dataset stats fused via fence + done-counter; last block computes norm.
__global__ __launch_bounds__(512, 3) void bucket_kernel(
        const int* __restrict__ cursor,
        const unsigned int* __restrict__ slots,
        const float4* __restrict__ sp4,
        const float* __restrict__ qp,
        float* __restrict__ feats,
        float* __restrict__ psum,
        float* __restrict__ psumsq,
        int* __restrict__ done,
        float* __restrict__ norm) {
    __shared__ unsigned int s_sorted[CAPB];   // 18 KB
    __shared__ float qtile[QPB * 3];
    __shared__ int s_cnt[QPB], s_start[QPB], s_cur[QPB];
    __shared__ float s_part[4][QPB][13];      // 26 KB: 12 sums + pad
    __shared__ float s_red1[8][9], s_red2[8][9];
    __shared__ int s_last;

    int tid = threadIdx.x;
    int b = blockIdx.x;
    int cnt = cursor[b * CSTR];
    if (cnt > CAPB) cnt = CAPB;

    if (tid < QPB) s_cnt[tid] = 0;
    for (int i = tid; i < QPB * 3; i += 512) {
        int g = b * QPB * 3 + i;
        qtile[i] = (g < Q_NODES * 3) ? qp[g] : 0.0f;
    }
    __syncthreads();

    const unsigned int* bslots = slots + b * CAPB;
    // histogram by query-within-bucket (int LDS atomics = native, fast)
    for (int i = tid; i < cnt; i += 512)
        atomicAdd(&s_cnt[bslots[i] >> 17], 1);
    __syncthreads();

    // exclusive scan of 128 counts by wave 0 (2 elements/lane, shfl scan)
    if (tid < 64) {
        int a0 = s_cnt[tid], a1 = s_cnt[64 + tid];
        int i0 = a0, i1 = a1;
#pragma unroll
        for (int off = 1; off < 64; off <<= 1) {
            int t0 = __shfl_up(i0, off); if (tid >= off) i0 += t0;
            int t1 = __shfl_up(i1, off); if (tid >= off) i1 += t1;
        }
        int tot0 = __shfl(i0, 63);
        s_start[tid] = i0 - a0;              s_cur[tid] = i0 - a0;
        s_start[64 + tid] = i1 - a1 + tot0;  s_cur[64 + tid] = i1 - a1 + tot0;
    }
    __syncthreads();

    // counting-sort scatter into LDS
    for (int i = tid; i < cnt; i += 512) {
        unsigned rec = bslots[i];
        int pos = atomicAdd(&s_cur[rec >> 17], 1);
        s_sorted[pos] = rec;
    }
    __syncthreads();

    // accumulate: 4 threads per query, strided over the degree; deterministic
    // 4-way combine afterwards (no float atomics anywhere).
    {
        int q = tid & (QPB - 1);
        int sub = tid >> 7;                  // 0..3
        float qx = qtile[3 * q + 0], qy = qtile[3 * q + 1], qz = qtile[3 * q + 2];
        float s[12];
#pragma unroll
        for (int k = 0; k < 12; ++k) s[k] = 0.0f;
        int st = s_start[q], deg = s_cnt[q];
        for (int j = sub; j < deg; j += 4) {
            unsigned rec = s_sorted[st + j];
            float4 sv = sp4[rec & 0x1FFFF];
            float dx = sv.x - qx, dy = sv.y - qy, dz = sv.z - qz;
            float d2 = dx * dx + dy * dy + dz * dz;
            s[0] += 1.0f;
            s[1] += sqrtf(d2);
            s[2] += d2;
            s[3] += sv.x; s[4] += sv.y; s[5] += sv.z;
            s[6] += sv.x * sv.x; s[7] += sv.x * sv.y; s[8] += sv.x * sv.z;
            s[9] += sv.y * sv.y; s[10] += sv.y * sv.z; s[11] += sv.z * sv.z;
        }
#pragma unroll
        for (int k = 0; k < 12; ++k) s_part[sub][q][k] = s[k];
    }
    __syncthreads();

    // per-query finalize by threads 0..127
    float f[9];
#pragma unroll
    for (int k = 0; k < 9; ++k) f[k] = 0.0f;
    int q = b * QPB + (tid & (QPB - 1));
    if (tid < QPB && q < Q_NODES) {
        float qx = qtile[3 * tid + 0], qy = qtile[3 * tid + 1], qz = qtile[3 * tid + 2];
        float s[12];
#pragma unroll
        for (int k = 0; k < 12; ++k)
            s[k] = ((s_part[0][tid][k] + s_part[1][tid][k])
                  + (s_part[2][tid][k] + s_part[3][tid][k]));
        sums_to_feats(s, qx, qy, qz, f);
#pragma unroll
        for (int k = 0; k < 9; ++k) feats[k * Q_NODES + q] = f[k];  // coalesced per k
    }

    // dataset-wide stats: wave reduce -> LDS -> one partial row per block
    int lane = tid & 63, wv = tid >> 6;
#pragma unroll
    for (int k = 0; k < 9; ++k) {
        float s1 = f[k];
        float s2 = f[k] * f[k];
#pragma unroll
        for (int off = 32; off > 0; off >>= 1) {
            s1 += __shfl_down(s1, off);
            s2 += __shfl_down(s2, off);
        }
        if (lane == 0) { s_red1[wv][k] = s1; s_red2[wv][k] = s2; }
    }
    __syncthreads();
    if (tid < 9) {
        float t1 = 0.0f, t2 = 0.0f;
#pragma unroll
        for (int w = 0; w < 8; ++w) { t1 += s_red1[w][tid]; t2 += s_red2[w][tid]; }
        psum[tid * NB + b]   = t1;
        psumsq[tid * NB + b] = t2;
    }
    __threadfence();                 // release partial rows device-wide
    __syncthreads();
    if (tid == 0) s_last = (atomicAdd(done, 1) == NB - 1);
    __syncthreads();
    if (s_last) {
        __threadfence();             // acquire other blocks' rows
        int k = tid >> 5, l32 = tid & 31;
        if (k < 9) {
            double a1 = 0.0, a2 = 0.0;
            for (int bb = l32; bb < NB; bb += 32) {
                a1 += (double)psum[k * NB + bb];
                a2 += (double)psumsq[k * NB + bb];
            }
#pragma unroll
            for (int off = 16; off > 0; off >>= 1) {
                a1 += __shfl_down(a1, off);
                a2 += __shfl_down(a2, off);
            }
            if (l32 == 0) {
                double S = a1, S2 = a2;
                double mean = S / (double)Q_NODES;
                double var = (S2 - S * S / (double)Q_NODES) / (double)(Q_NODES - 1);
                if (var < 0.0) var = 0.0;
                double sd = sqrt(var);
                if (sd < 1e-6) sd = 1.0;
                norm[k] = (float)mean;
                norm[9 + k] = (float)(1.0 / sd);
            }
        }
    }
}

// ============================================================================
// MLP: 512 threads, single pass over all 128 outputs. 73 KB LDS -> 2 blocks/CU
// (16 waves/CU). Raw feats staged to LDS early (coalesced), W2^T via float4.
// ============================================================================

__global__ __launch_bounds__(512, 2) void mlp_kernel(
        const float* __restrict__ feats,
        const float* __restrict__ norm,
        const float* __restrict__ W1, const float* __restrict__ b1,
        const float* __restrict__ W2, const float* __restrict__ b2,
        float* __restrict__ out) {
    __shared__ float sW1[576];        // [64][9]
    __shared__ float sB1[64];
    __shared__ float sB2[128];
    __shared__ float sNorm[18];
    __shared__ float sfeat[9 * 128];  // raw feats [k][q]
    __shared__ float w2t[64 * 128];   // [k][o]
    __shared__ float ht[64 * 128];    // [k][q]

    int tid = threadIdx.x;
    int blk_q = blockIdx.x;

    // issue feats loads first: coalesced, latency hides under weight staging
    for (int i = tid; i < 9 * 128; i += 512) {
        int k = i >> 7, qq = i & 127;
        int qg = blk_q * 128 + qq;
        if (qg >= Q_NODES) qg = Q_NODES - 1;
        sfeat[i] = feats[k * Q_NODES + qg];
    }

    // W2^T staging: thread owns column o = tid&127, 16 k's via 4 float4 loads
    {
        int o = tid & 127, kb = (tid >> 7) * 16;
        const float4* w2v = (const float4*)(W2 + o * 64 + kb);
#pragma unroll
        for (int j = 0; j < 4; ++j) {
            float4 w = w2v[j];
            int k = kb + j * 4;
            w2t[(k + 0) * 128 + o] = w.x;
            w2t[(k + 1) * 128 + o] = w.y;
            w2t[(k + 2) * 128 + o] = w.z;
            w2t[(k + 3) * 128 + o] = w.w;
        }
    }
    for (int i = tid; i < 576; i += 512) sW1[i] = W1[i];
    if (tid < 64) sB1[tid] = b1[tid];
    if (tid < 128) sB2[tid] = b2[tid];
    if (tid < 18) sNorm[tid] = norm[tid];
    __syncthreads();

    // Layer 1: q = tid&127, quarter = tid>>7 -> 16 h-rows each
    {
        int qq = tid & 127, quarter = tid >> 7;
        float f[9];
#pragma unroll
        for (int k = 0; k < 9; ++k)
            f[k] = (sfeat[k * 128 + qq] - sNorm[k]) * sNorm[9 + k];
#pragma unroll 4
        for (int j = 0; j < 16; ++j) {
            int ko = quarter * 16 + j;
            float a = sB1[ko];
#pragma unroll
            for (int kf = 0; kf < 9; ++kf) a = fmaf(f[kf], sW1[ko * 9 + kf], a);
            ht[ko * 128 + qq] = fmaxf(a, 0.0f);   // lanes span q -> conflict-free
        }
    }
    __syncthreads();

    // Layer 2: thread tile 8q x 4o; qt in [0,16), ot in [0,32)
    int qt = tid >> 5, ot = tid & 31;
    int q0 = qt * 8, o0 = ot * 4;
    float acc[8][4];
#pragma unroll
    for (int i = 0; i < 8; ++i)
#pragma unroll
        for (int j = 0; j < 4; ++j) acc[i][j] = 0.0f;

#pragma unroll 4
    for (int k = 0; k < 64; ++k) {
        float4 h0 = *(const float4*)&ht[k * 128 + q0];       // 2-addr broadcast
        float4 h1 = *(const float4*)&ht[k * 128 + q0 + 4];
        float4 w  = *(const float4*)&w2t[k * 128 + o0];      // 4-way, cheap
        float hh[8] = { h0.x, h0.y, h0.z, h0.w, h1.x, h1.y, h1.z, h1.w };
#pragma unroll
        for (int i = 0; i < 8; ++i) {
            acc[i][0] = fmaf(hh[i], w.x, acc[i][0]);
            acc[i][1] = fmaf(hh[i], w.y, acc[i][1]);
            acc[i][2] = fmaf(hh[i], w.z, acc[i][2]);
            acc[i][3] = fmaf(hh[i], w.w, acc[i][3]);
        }
    }

    float4 bb = *(const float4*)&sB2[o0];
#pragma unroll
    for (int i = 0; i < 8; ++i) {
        int qg = blk_q * 128 + q0 + i;
        if (qg < Q_NODES) {
            float4 vv = make_float4(acc[i][0] + bb.x, acc[i][1] + bb.y,
                                    acc[i][2] + bb.z, acc[i][3] + bb.w);
            *(float4*)(out + (size_t)qg * 128 + o0) = vv;
        }
    }
}

// ============================================================================
// FALLBACK PATH (round-1 algorithm, used only if ws_size too small)
// ============================================================================

__global__ __launch_bounds__(256) void edge_kernel(
        const int* __restrict__ edge,
        const float* __restrict__ sp,
        const float* __restrict__ qp,
        float* __restrict__ acc) {
    int e = blockIdx.x * 256 + threadIdx.x;
    if (e >= N_EDGES) return;
    int q = edge[e];
    int s = edge[N_EDGES + e];
    float sx = sp[3 * s + 0], sy = sp[3 * s + 1], sz = sp[3 * s + 2];
    float qx = qp[3 * q + 0], qy = qp[3 * q + 1], qz = qp[3 * q + 2];
    float dx = sx - qx, dy = sy - qy, dz = sz - qz;
    float d2 = dx * dx + dy * dy + dz * dz;
    atomAddF(acc + 0 * Q_NODES + q, 1.0f);
    atomAddF(acc + 1 * Q_NODES + q, sqrtf(d2));
    atomAddF(acc + 2 * Q_NODES + q, d2);
    atomAddF(acc + 3 * Q_NODES + q, sx);
    atomAddF(acc + 4 * Q_NODES + q, sy);
    atomAddF(acc + 5 * Q_NODES + q, sz);
    atomAddF(acc + 6 * Q_NODES + q, sx * sx);
    atomAddF(acc + 7 * Q_NODES + q, sx * sy);
    atomAddF(acc + 8 * Q_NODES + q, sx * sz);
    atomAddF(acc + 9 * Q_NODES + q, sy * sy);
    atomAddF(acc + 10 * Q_NODES + q, sy * sz);
    atomAddF(acc + 11 * Q_NODES + q, sz * sz);
}

__global__ __launch_bounds__(256) void finalize_kernel(
        const float* __restrict__ acc,
        const float* __restrict__ qp,
        float* __restrict__ feats,
        double* __restrict__ stats) {
    int q = blockIdx.x * 256 + threadIdx.x;
    float f[9];
#pragma unroll
    for (int k = 0; k < 9; ++k) f[k] = 0.0f;
    if (q < Q_NODES) {
        float s[12];
#pragma unroll
        for (int k = 0; k < 12; ++k) s[k] = acc[k * Q_NODES + q];
        float qx = qp[3 * q + 0], qy = qp[3 * q + 1], qz = qp[3 * q + 2];
        sums_to_feats(s, qx, qy, qz, f);
#pragma unroll
        for (int k = 0; k < 9; ++k) feats[k * Q_NODES + q] = f[k];
    }
    int lane = threadIdx.x & 63;
#pragma unroll
    for (int k = 0; k < 9; ++k) {
        float s1 = f[k];
        float s2 = f[k] * f[k];
#pragma unroll
        for (int off = 32; off > 0; off >>= 1) {
            s1 += __shfl_down(s1, off);
            s2 += __shfl_down(s2, off);
        }
        if (lane == 0) {
            atomicAdd(&stats[k], (double)s1);
            atomicAdd(&stats[9 + k], (double)s2);
        }
    }
}

__global__ void stats_kernel(const double* __restrict__ stats,
                             float* __restrict__ norm) {
    int k = threadIdx.x;
    if (k < 9) {
        double S = stats[k], S2 = stats[9 + k];
        double mean = S / (double)Q_NODES;
        double var = (S2 - S * S / (double)Q_NODES) / (double)(Q_NODES - 1);
        if (var < 0.0) var = 0.0;
        double sd = sqrt(var);
        if (sd < 1e-6) sd = 1.0;
        norm[k] = (float)mean;
        norm[9 + k] = (float)(1.0 / sd);
    }
}

// ============================================================================

extern "C" void kernel_launch(void* const* d_in, const int* in_sizes, int n_in,
                              void* d_out, int out_size, void* d_ws, size_t ws_size,
                              hipStream_t stream) {
    const float* sp   = (const float*)d_in[0];
    const float* qp   = (const float*)d_in[1];
    const int*   edge = (const int*)d_in[2];
    const float* W1   = (const float*)d_in[3];
    const float* b1   = (const float*)d_in[4];
    const float* W2   = (const float*)d_in[5];
    const float* b2   = (const float*)d_in[6];
    float* out = (float*)d_out;
    char* ws = (char*)d_ws;

    if (ws_size >= F_WS_NEED) {
        int*          cursor = (int*)(ws + F_CURSOR_OFF);
        int*          done   = (int*)(ws + F_DONE_OFF);
        float*        norm   = (float*)(ws + F_NORM_OFF);
        float*        psum   = (float*)(ws + F_PSUM_OFF);
        float*        psumsq = (float*)(ws + F_PSUMSQ_OFF);
        float*        feats  = (float*)(ws + F_FEATS_OFF);
        float4*       sp4    = (float4*)(ws + F_SP4_OFF);
        unsigned int* slots  = (unsigned int*)(ws + F_SLOTS_OFF);

        hipMemsetAsync(ws, 0, F_ZERO_BYTES, stream);
        partition_kernel<<<(N_EDGES + TILE - 1) / TILE, 512, 0, stream>>>(
            edge, sp, sp4, cursor, slots);
        bucket_kernel<<<NB, 512, 0, stream>>>(
            cursor, slots, sp4, qp, feats, psum, psumsq, done, norm);
        mlp_kernel<<<NB, 512, 0, stream>>>(feats, norm, W1, b1, W2, b2, out);
    } else {
        float*  acc   = (float*)(ws + B_ACC_OFF);
        double* stats = (double*)(ws + B_STATS_OFF);
        float*  norm  = (float*)(ws + B_NORM_OFF);
        float*  feats = (float*)(ws + B_FEATS_OFF);

        hipMemsetAsync(ws, 0, B_ZERO_BYTES, stream);
        edge_kernel<<<N_EDGES / 256, 256, 0, stream>>>(edge, sp, qp, acc);
        finalize_kernel<<<(Q_NODES + 255) / 256, 256, 0, stream>>>(acc, qp, feats, stats);
        stats_kernel<<<1, 64, 0, stream>>>(stats, norm);
        mlp_kernel<<<NB, 512, 0, stream>>>(feats, norm, W1, b1, W2, b2, out);
    }
}

// Round 4
// 206.621 us; speedup vs baseline: 2.3186x; 1.5191x over previous
//
#include <hip/hip_runtime.h>
#include <math.h>

#define Q_NODES 100000
#define S_NODES 100000
#define N_EDGES 3200000
#define HIDDEN 64
#define OUT_DIM 128

// ---------- bucket partition parameters ----------
#define QPB   128                    // queries per bucket (bucket = q >> 7)
#define NB    782                    // ceil(Q_NODES / QPB)
#define CAPB  4608                   // bucket capacity: mean 4096, +8 sigma
#define TILE  4096                   // edges per partition block
#define NT4   (N_EDGES / 4)          // int4 count per edge row
#define CSTR  16                     // cursor stride (ints) -> one 64B line per bucket

// ---------- FAST-PATH workspace layout (bytes) ----------
#define F_CURSOR_OFF 0               // 782 * 64 B (padded: 1 cacheline per bucket)
#define F_DONE_OFF   50048
#define F_NORM_OFF   50112
#define F_PSUM_OFF   50240
#define F_PSUMSQ_OFF 78400
#define F_FEATS_OFF  106560
#define F_SP4_OFF    3706560
#define F_SLOTS_OFF  5306560
#define F_ZERO_BYTES 50052           // cursor (+ unused done word)
#define F_WS_NEED    (5306560ull + (unsigned long long)(NB * CAPB + 1) * 4)

// ---------- FALLBACK workspace layout (round-1 algorithm) ----------
#define B_ACC_OFF    0
#define B_STATS_OFF  4800000
#define B_NORM_OFF   4800144
#define B_FEATS_OFF  4800224
#define B_ZERO_BYTES 4800144

__device__ __forceinline__ void atomAddF(float* p, float v) {
#if defined(__gfx950__) || defined(__gfx942__) || defined(__gfx90a__)
    unsafeAtomicAdd(p, v);
#else
    atomicAdd(p, v);
#endif
}

// ============================================================================
// Shared device helpers
// ============================================================================

__device__ __forceinline__ void eig3_sym(
        float a00, float a01, float a02, float a11, float a12, float a22,
        float& e1, float& e2, float& e3) {
    float p1 = a01 * a01 + a02 * a02 + a12 * a12;
    float qm = (a00 + a11 + a22) * (1.0f / 3.0f);
    float b00 = a00 - qm, b11 = a11 - qm, b22 = a22 - qm;
    float p2 = b00 * b00 + b11 * b11 + b22 * b22 + 2.0f * p1;
    if (p2 <= 1e-24f) {
        e1 = qm; e2 = qm; e3 = qm;
    } else {
        float p = sqrtf(p2 * (1.0f / 6.0f));
        float invp = 1.0f / p;
        float c00 = b00 * invp, c11 = b11 * invp, c22 = b22 * invp;
        float c01 = a01 * invp, c02 = a02 * invp, c12 = a12 * invp;
        float detB = c00 * (c11 * c22 - c12 * c12)
                   - c01 * (c01 * c22 - c12 * c02)
                   + c02 * (c01 * c12 - c11 * c02);
        float r = 0.5f * detB;
        r = fminf(fmaxf(r, -1.0f), 1.0f);
        float phi = acosf(r) * (1.0f / 3.0f);
        e1 = qm + 2.0f * p * cosf(phi);
        e3 = qm + 2.0f * p * cosf(phi + 2.0943951023931953f); // +2pi/3
        e2 = 3.0f * qm - e1 - e3;
    }
}

// sums: n,sumd,sumd2,sx,sy,sz,xx,xy,xz,yy,yz,zz -> 9 features
__device__ __forceinline__ void sums_to_feats(
        const float* s, float qx, float qy, float qz, float* f) {
    float n = s[0];
#pragma unroll
    for (int k = 0; k < 9; ++k) f[k] = 0.0f;
    if (n > 0.0f) {
        float inv = 1.0f / n;
        float Davg = s[1] * inv;
        float Dvar = fmaxf(s[2] * inv - Davg * Davg, 0.0f);
        float cx = s[3] * inv, cy = s[4] * inv, cz = s[5] * inv;
        float a00 = fmaxf(s[6] * inv - cx * cx, 0.0f);
        float a01 = s[7] * inv - cx * cy;
        float a02 = s[8] * inv - cx * cz;
        float a11 = fmaxf(s[9] * inv - cy * cy, 0.0f);
        float a12 = s[10] * inv - cy * cz;
        float a22 = fmaxf(s[11] * inv - cz * cz, 0.0f);
        float e1, e2, e3;
        eig3_sym(a00, a01, a02, a11, a12, a22, e1, e2, e3);
        f[0] = n; f[1] = Davg; f[2] = Dvar;
        f[3] = cx - qx; f[4] = cy - qy; f[5] = cz - qz;
        f[6] = e1; f[7] = e2; f[8] = e3;
    }
}

// ============================================================================
// FAST PATH
// ============================================================================

__global__ __launch_bounds__(512, 4) void partition_kernel(
        const int* __restrict__ edge,
        const float* __restrict__ sp,
        float4* __restrict__ sp4,
        int* __restrict__ cursor,
        unsigned int* __restrict__ slots) {
    __shared__ unsigned int s_rec[TILE];   // 16 KB: packed records, bucket-sorted
    __shared__ int s_posh[TILE];           // 16 KB: phase A = histogram[NB]; phase B = dest idx
    __shared__ int s_cur[NB];
    __shared__ int s_off[NB];
    __shared__ int s_wsum[8];

    int tid = threadIdx.x;
    int lane = tid & 63, wv = tid >> 6;
    int tileStart = blockIdx.x * TILE;
    int tileCount = N_EDGES - tileStart;
    if (tileCount > TILE) tileCount = TILE;

    // fused sp -> sp4 pad
    {
        int i = blockIdx.x * 512 + tid;
        if (i < S_NODES)
            sp4[i] = make_float4(sp[3 * i], sp[3 * i + 1], sp[3 * i + 2], 0.0f);
    }

    for (int b = tid; b < NB; b += 512) s_posh[b] = 0;
    __syncthreads();

    const int4* eq4 = (const int4*)edge;
    const int4* es4 = (const int4*)(edge + N_EDGES);
    int base4 = blockIdx.x * (TILE / 4);
    int4 q4[2], s4[2];
    bool v[2];
#pragma unroll
    for (int j = 0; j < 2; ++j) {
        int i4 = base4 + tid + j * 512;
        v[j] = i4 < NT4;
        int ic = v[j] ? i4 : 0;
        q4[j] = eq4[ic];
        s4[j] = es4[ic];
        if (v[j]) {
            atomicAdd(&s_posh[q4[j].x >> 7], 1);
            atomicAdd(&s_posh[q4[j].y >> 7], 1);
            atomicAdd(&s_posh[q4[j].z >> 7], 1);
            atomicAdd(&s_posh[q4[j].w >> 7], 1);
        }
    }
    __syncthreads();

    // exclusive prefix of histogram -> s_cur
    int local[4], tsum = 0;
#pragma unroll
    for (int j = 0; j < 4; ++j) {
        int idx = 4 * tid + j;
        local[j] = (idx < NB) ? s_posh[idx] : 0;
        tsum += local[j];
    }
    int inc = tsum;
#pragma unroll
    for (int off = 1; off < 64; off <<= 1) {
        int t = __shfl_up(inc, off);
        if (lane >= off) inc += t;
    }
    if (lane == 63) s_wsum[wv] = inc;
    __syncthreads();
    int wbase = 0;
    for (int w = 0; w < wv; ++w) wbase += s_wsum[w];
    int run = wbase + inc - tsum;
#pragma unroll
    for (int j = 0; j < 4; ++j) {
        int idx = 4 * tid + j;
        if (idx < NB) s_cur[idx] = run;
        run += local[j];
    }
    __syncthreads();

    // reserve global space per non-empty bucket (padded cursor: 1 line/bucket)
    for (int b = tid; b < NB; b += 512) {
        int c = s_posh[b];
        int base = c ? atomicAdd(&cursor[b * CSTR], c) : 0;
        s_off[b] = b * CAPB + base - s_cur[b];
    }
    __syncthreads();   // histogram region of s_posh is now dead

    // scatter into bucket-sorted LDS stage, computing global dest on the fly
#pragma unroll
    for (int j = 0; j < 2; ++j) {
        if (v[j]) {
            int qs[4] = { q4[j].x, q4[j].y, q4[j].z, q4[j].w };
            int ss[4] = { s4[j].x, s4[j].y, s4[j].z, s4[j].w };
#pragma unroll
            for (int m = 0; m < 4; ++m) {
                int bkt = qs[m] >> 7;
                int idx = atomicAdd(&s_cur[bkt], 1);
                int gpos = idx + s_off[bkt];
                if (gpos >= (bkt + 1) * CAPB) gpos = NB * CAPB;  // overflow guard
                s_rec[idx] = ((unsigned)(qs[m] & (QPB - 1)) << 17) | (unsigned)ss[m];
                s_posh[idx] = gpos;
            }
        }
    }
    __syncthreads();

    // write-out: bucket-contiguous runs -> mostly coalesced
    for (int i = tid; i < tileCount; i += 512)
        slots[s_posh[i]] = s_rec[i];
}

// Sort-based accumulate (round-1 proven, NO fence/fusion tail): LDS counting
// sort, then 4 threads per query over contiguous runs, register sums,
// deterministic combine. Per-block stats partials to global; separate reduce.
__global__ __launch_bounds__(512) void bucket_kernel(
        const int* __restrict__ cursor,
        const unsigned int* __restrict__ slots,
        const float4* __restrict__ sp4,
        const float* __restrict__ qp,
        float* __restrict__ feats,
        float* __restrict__ psum,
        float* __restrict__ psumsq) {
    __shared__ unsigned int s_sorted[CAPB];   // 18 KB
    __shared__ float qtile[QPB * 3];
    __shared__ int s_cnt[QPB], s_start[QPB], s_cur[QPB];
    __shared__ float s_part[4][QPB][13];      // 26 KB: 12 sums + pad
    __shared__ float s_red1[8][9], s_red2[8][9];

    int tid = threadIdx.x;
    int b = blockIdx.x;
    int cnt = cursor[b * CSTR];
    if (cnt > CAPB) cnt = CAPB;

    if (tid < QPB) s_cnt[tid] = 0;
    for (int i = tid; i < QPB * 3; i += 512) {
        int g = b * QPB * 3 + i;
        qtile[i] = (g < Q_NODES * 3) ? qp[g] : 0.0f;
    }
    __syncthreads();

    const unsigned int* bslots = slots + b * CAPB;
    // histogram by query-within-bucket (int LDS atomics = native, fast)
    for (int i = tid; i < cnt; i += 512)
        atomicAdd(&s_cnt[bslots[i] >> 17], 1);
    __syncthreads();

    // exclusive scan of 128 counts by wave 0 (2 elements/lane, shfl scan)
    if (tid < 64) {
        int a0 = s_cnt[tid], a1 = s_cnt[64 + tid];
        int i0 = a0, i1 = a1;
#pragma unroll
        for (int off = 1; off < 64; off <<= 1) {
            int t0 = __shfl_up(i0, off); if (tid >= off) i0 += t0;
            int t1 = __shfl_up(i1, off); if (tid >= off) i1 += t1;
        }
        int tot0 = __shfl(i0, 63);
        s_start[tid] = i0 - a0;              s_cur[tid] = i0 - a0;
        s_start[64 + tid] = i1 - a1 + tot0;  s_cur[64 + tid] = i1 - a1 + tot0;
    }
    __syncthreads();

    // counting-sort scatter into LDS
    for (int i = tid; i < cnt; i += 512) {
        unsigned rec = bslots[i];
        int pos = atomicAdd(&s_cur[rec >> 17], 1);
        s_sorted[pos] = rec;
    }
    __syncthreads();

    // accumulate: 4 threads per query, strided over the degree; deterministic
    // 4-way combine afterwards (no float atomics anywhere).
    {
        int q = tid & (QPB - 1);
        int sub = tid >> 7;                  // 0..3
        float qx = qtile[3 * q + 0], qy = qtile[3 * q + 1], qz = qtile[3 * q + 2];
        float s[12];
#pragma unroll
        for (int k = 0; k < 12; ++k) s[k] = 0.0f;
        int st = s_start[q], deg = s_cnt[q];
        for (int j = sub; j < deg; j += 4) {
            unsigned rec = s_sorted[st + j];
            float4 sv = sp4[rec & 0x1FFFF];
            float dx = sv.x - qx, dy = sv.y - qy, dz = sv.z - qz;
            float d2 = dx * dx + dy * dy + dz * dz;
            s[0] += 1.0f;
            s[1] += sqrtf(d2);
            s[2] += d2;
            s[3] += sv.x; s[4] += sv.y; s[5] += sv.z;
            s[6] += sv.x * sv.x; s[7] += sv.x * sv.y; s[8] += sv.x * sv.z;
            s[9] += sv.y * sv.y; s[10] += sv.y * sv.z; s[11] += sv.z * sv.z;
        }
#pragma unroll
        for (int k = 0; k < 12; ++k) s_part[sub][q][k] = s[k];
    }
    __syncthreads();

    // per-query finalize by threads 0..127
    float f[9];
#pragma unroll
    for (int k = 0; k < 9; ++k) f[k] = 0.0f;
    int q = b * QPB + (tid & (QPB - 1));
    if (tid < QPB && q < Q_NODES) {
        float qx = qtile[3 * tid + 0], qy = qtile[3 * tid + 1], qz = qtile[3 * tid + 2];
        float s[12];
#pragma unroll
        for (int k = 0; k < 12; ++k)
            s[k] = ((s_part[0][tid][k] + s_part[1][tid][k])
                  + (s_part[2][tid][k] + s_part[3][tid][k]));
        sums_to_feats(s, qx, qy, qz, f);
#pragma unroll
        for (int k = 0; k < 9; ++k) feats[k * Q_NODES + q] = f[k];  // coalesced per k
    }

    // dataset-wide stats: wave reduce -> LDS -> one partial row per block
    int lane = tid & 63, wv = tid >> 6;
#pragma unroll
    for (int k = 0; k < 9; ++k) {
        float s1 = f[k];
        float s2 = f[k] * f[k];
#pragma unroll
        for (int off = 32; off > 0; off >>= 1) {
            s1 += __shfl_down(s1, off);
            s2 += __shfl_down(s2, off);
        }
        if (lane == 0) { s_red1[wv][k] = s1; s_red2[wv][k] = s2; }
    }
    __syncthreads();
    if (tid < 9) {
        float t1 = 0.0f, t2 = 0.0f;
#pragma unroll
        for (int w = 0; w < 8; ++w) { t1 += s_red1[w][tid]; t2 += s_red2[w][tid]; }
        psum[tid * NB + b]   = t1;
        psumsq[tid * NB + b] = t2;
    }
}

// 9 waves, one per feature column; no barriers.
__global__ __launch_bounds__(576) void stats_reduce_kernel(
        const float* __restrict__ psum,
        const float* __restrict__ psumsq,
        float* __restrict__ norm) {
    int k = threadIdx.x >> 6, lane = threadIdx.x & 63;
    if (k >= 9) return;
    double a1 = 0.0, a2 = 0.0;
    for (int b = lane; b < NB; b += 64) {
        a1 += (double)psum[k * NB + b];
        a2 += (double)psumsq[k * NB + b];
    }
#pragma unroll
    for (int off = 32; off > 0; off >>= 1) {
        a1 += __shfl_down(a1, off);
        a2 += __shfl_down(a2, off);
    }
    if (lane == 0) {
        double S = a1, S2 = a2;
        double mean = S / (double)Q_NODES;
        double var = (S2 - S * S / (double)Q_NODES) / (double)(Q_NODES - 1);
        if (var < 0.0) var = 0.0;
        double sd = sqrt(var);
        if (sd < 1e-6) sd = 1.0;
        norm[k] = (float)mean;
        norm[9 + k] = (float)(1.0 / sd);
    }
}

// ============================================================================
// MLP: 512 threads, single pass over all 128 outputs. 73 KB LDS -> 2 blocks/CU
// (16 waves/CU). Raw feats staged to LDS early (coalesced), W2^T via float4.
// ============================================================================

__global__ __launch_bounds__(512, 2) void mlp_kernel(
        const float* __restrict__ feats,
        const float* __restrict__ norm,
        const float* __restrict__ W1, const float* __restrict__ b1,
        const float* __restrict__ W2, const float* __restrict__ b2,
        float* __restrict__ out) {
    __shared__ float sW1[576];        // [64][9]
    __shared__ float sB1[64];
    __shared__ float sB2[128];
    __shared__ float sNorm[18];
    __shared__ float sfeat[9 * 128];  // raw feats [k][q]
    __shared__ float w2t[64 * 128];   // [k][o]
    __shared__ float ht[64 * 128];    // [k][q]

    int tid = threadIdx.x;
    int blk_q = blockIdx.x;

    // issue feats loads first: coalesced, latency hides under weight staging
    for (int i = tid; i < 9 * 128; i += 512) {
        int k = i >> 7, qq = i & 127;
        int qg = blk_q * 128 + qq;
        if (qg >= Q_NODES) qg = Q_NODES - 1;
        sfeat[i] = feats[k * Q_NODES + qg];
    }

    // W2^T staging: thread owns column o = tid&127, 16 k's via 4 float4 loads
    {
        int o = tid & 127, kb = (tid >> 7) * 16;
        const float4* w2v = (const float4*)(W2 + o * 64 + kb);
#pragma unroll
        for (int j = 0; j < 4; ++j) {
            float4 w = w2v[j];
            int k = kb + j * 4;
            w2t[(k + 0) * 128 + o] = w.x;
            w2t[(k + 1) * 128 + o] = w.y;
            w2t[(k + 2) * 128 + o] = w.z;
            w2t[(k + 3) * 128 + o] = w.w;
        }
    }
    for (int i = tid; i < 576; i += 512) sW1[i] = W1[i];
    if (tid < 64) sB1[tid] = b1[tid];
    if (tid < 128) sB2[tid] = b2[tid];
    if (tid < 18) sNorm[tid] = norm[tid];
    __syncthreads();

    // Layer 1: q = tid&127, quarter = tid>>7 -> 16 h-rows each
    {
        int qq = tid & 127, quarter = tid >> 7;
        float f[9];
#pragma unroll
        for (int k = 0; k < 9; ++k)
            f[k] = (sfeat[k * 128 + qq] - sNorm[k]) * sNorm[9 + k];
#pragma unroll 4
        for (int j = 0; j < 16; ++j) {
            int ko = quarter * 16 + j;
            float a = sB1[ko];
#pragma unroll
            for (int kf = 0; kf < 9; ++kf) a = fmaf(f[kf], sW1[ko * 9 + kf], a);
            ht[ko * 128 + qq] = fmaxf(a, 0.0f);   // lanes span q -> conflict-free
        }
    }
    __syncthreads();

    // Layer 2: thread tile 8q x 4o; qt in [0,16), ot in [0,32)
    int qt = tid >> 5, ot = tid & 31;
    int q0 = qt * 8, o0 = ot * 4;
    float acc[8][4];
#pragma unroll
    for (int i = 0; i < 8; ++i)
#pragma unroll
        for (int j = 0; j < 4; ++j) acc[i][j] = 0.0f;

#pragma unroll 4
    for (int k = 0; k < 64; ++k) {
        float4 h0 = *(const float4*)&ht[k * 128 + q0];       // 2-addr broadcast
        float4 h1 = *(const float4*)&ht[k * 128 + q0 + 4];
        float4 w  = *(const float4*)&w2t[k * 128 + o0];      // 4-way, cheap
        float hh[8] = { h0.x, h0.y, h0.z, h0.w, h1.x, h1.y, h1.z, h1.w };
#pragma unroll
        for (int i = 0; i < 8; ++i) {
            acc[i][0] = fmaf(hh[i], w.x, acc[i][0]);
            acc[i][1] = fmaf(hh[i], w.y, acc[i][1]);
            acc[i][2] = fmaf(hh[i], w.z, acc[i][2]);
            acc[i][3] = fmaf(hh[i], w.w, acc[i][3]);
        }
    }

    float4 bb = *(const float4*)&sB2[o0];
#pragma unroll
    for (int i = 0; i < 8; ++i) {
        int qg = blk_q * 128 + q0 + i;
        if (qg < Q_NODES) {
            float4 vv = make_float4(acc[i][0] + bb.x, acc[i][1] + bb.y,
                                    acc[i][2] + bb.z, acc[i][3] + bb.w);
            *(float4*)(out + (size_t)qg * 128 + o0) = vv;
        }
    }
}

// ============================================================================
// FALLBACK PATH (round-1 algorithm, used only if ws_size too small)
// ============================================================================

__global__ __launch_bounds__(256) void edge_kernel(
        const int* __restrict__ edge,
        const float* __restrict__ sp,
        const float* __restrict__ qp,
        float* __restrict__ acc) {
    int e = blockIdx.x * 256 + threadIdx.x;
    if (e >= N_EDGES) return;
    int q = edge[e];
    int s = edge[N_EDGES + e];
    float sx = sp[3 * s + 0], sy = sp[3 * s + 1], sz = sp[3 * s + 2];
    float qx = qp[3 * q + 0], qy = qp[3 * q + 1], qz = qp[3 * q + 2];
    float dx = sx - qx, dy = sy - qy, dz = sz - qz;
    float d2 = dx * dx + dy * dy + dz * dz;
    atomAddF(acc + 0 * Q_NODES + q, 1.0f);
    atomAddF(acc + 1 * Q_NODES + q, sqrtf(d2));
    atomAddF(acc + 2 * Q_NODES + q, d2);
    atomAddF(acc + 3 * Q_NODES + q, sx);
    atomAddF(acc + 4 * Q_NODES + q, sy);
    atomAddF(acc + 5 * Q_NODES + q, sz);
    atomAddF(acc + 6 * Q_NODES + q, sx * sx);
    atomAddF(acc + 7 * Q_NODES + q, sx * sy);
    atomAddF(acc + 8 * Q_NODES + q, sx * sz);
    atomAddF(acc + 9 * Q_NODES + q, sy * sy);
    atomAddF(acc + 10 * Q_NODES + q, sy * sz);
    atomAddF(acc + 11 * Q_NODES + q, sz * sz);
}

__global__ __launch_bounds__(256) void finalize_kernel(
        const float* __restrict__ acc,
        const float* __restrict__ qp,
        float* __restrict__ feats,
        double* __restrict__ stats) {
    int q = blockIdx.x * 256 + threadIdx.x;
    float f[9];
#pragma unroll
    for (int k = 0; k < 9; ++k) f[k] = 0.0f;
    if (q < Q_NODES) {
        float s[12];
#pragma unroll
        for (int k = 0; k < 12; ++k) s[k] = acc[k * Q_NODES + q];
        float qx = qp[3 * q + 0], qy = qp[3 * q + 1], qz = qp[3 * q + 2];
        sums_to_feats(s, qx, qy, qz, f);
#pragma unroll
        for (int k = 0; k < 9; ++k) feats[k * Q_NODES + q] = f[k];
    }
    int lane = threadIdx.x & 63;
#pragma unroll
    for (int k = 0; k < 9; ++k) {
        float s1 = f[k];
        float s2 = f[k] * f[k];
#pragma unroll
        for (int off = 32; off > 0; off >>= 1) {
            s1 += __shfl_down(s1, off);
            s2 += __shfl_down(s2, off);
        }
        if (lane == 0) {
            atomicAdd(&stats[k], (double)s1);
            atomicAdd(&stats[9 + k], (double)s2);
        }
    }
}

__global__ void stats_kernel(const double* __restrict__ stats,
                             float* __restrict__ norm) {
    int k = threadIdx.x;
    if (k < 9) {
        double S = stats[k], S2 = stats[9 + k];
        double mean = S / (double)Q_NODES;
        double var = (S2 - S * S / (double)Q_NODES) / (double)(Q_NODES - 1);
        if (var < 0.0) var = 0.0;
        double sd = sqrt(var);
        if (sd < 1e-6) sd = 1.0;
        norm[k] = (float)mean;
        norm[9 + k] = (float)(1.0 / sd);
    }
}

// ============================================================================

extern "C" void kernel_launch(void* const* d_in, const int* in_sizes, int n_in,
                              void* d_out, int out_size, void* d_ws, size_t ws_size,
                              hipStream_t stream) {
    const float* sp   = (const float*)d_in[0];
    const float* qp   = (const float*)d_in[1];
    const int*   edge = (const int*)d_in[2];
    const float* W1   = (const float*)d_in[3];
    const float* b1   = (const float*)d_in[4];
    const float* W2   = (const float*)d_in[5];
    const float* b2   = (const float*)d_in[6];
    float* out = (float*)d_out;
    char* ws = (char*)d_ws;

    if (ws_size >= F_WS_NEED) {
        int*          cursor = (int*)(ws + F_CURSOR_OFF);
        float*        norm   = (float*)(ws + F_NORM_OFF);
        float*        psum   = (float*)(ws + F_PSUM_OFF);
        float*        psumsq = (float*)(ws + F_PSUMSQ_OFF);
        float*        feats  = (float*)(ws + F_FEATS_OFF);
        float4*       sp4    = (float4*)(ws + F_SP4_OFF);
        unsigned int* slots  = (unsigned int*)(ws + F_SLOTS_OFF);

        hipMemsetAsync(ws, 0, F_ZERO_BYTES, stream);
        partition_kernel<<<(N_EDGES + TILE - 1) / TILE, 512, 0, stream>>>(
            edge, sp, sp4, cursor, slots);
        bucket_kernel<<<NB, 512, 0, stream>>>(
            cursor, slots, sp4, qp, feats, psum, psumsq);
        stats_reduce_kernel<<<1, 576, 0, stream>>>(psum, psumsq, norm);
        mlp_kernel<<<NB, 512, 0, stream>>>(feats, norm, W1, b1, W2, b2, out);
    } else {
        float*  acc   = (float*)(ws + B_ACC_OFF);
        double* stats = (double*)(ws + B_STATS_OFF);
        float*  norm  = (float*)(ws + B_NORM_OFF);
        float*  feats = (float*)(ws + B_FEATS_OFF);

        hipMemsetAsync(ws, 0, B_ZERO_BYTES, stream);
        edge_kernel<<<N_EDGES / 256, 256, 0, stream>>>(edge, sp, qp, acc);
        finalize_kernel<<<(Q_NODES + 255) / 256, 256, 0, stream>>>(acc, qp, feats, stats);
        stats_kernel<<<1, 64, 0, stream>>>(stats, norm);
        mlp_kernel<<<NB, 512, 0, stream>>>(feats, norm, W1, b1, W2, b2, out);
    }
}

// Round 5
// 183.835 us; speedup vs baseline: 2.6060x; 1.1239x over previous
//
#include <hip/hip_runtime.h>
#include <math.h>

#define Q_NODES 100000
#define S_NODES 100000
#define N_EDGES 3200000
#define HIDDEN 64
#define OUT_DIM 128

// ---------- bucket partition parameters ----------
#define QPB   128                    // queries per bucket (bucket = q >> 7)
#define NB    782                    // ceil(Q_NODES / QPB)
#define CAPB  4608                   // bucket capacity: mean 4096, +8 sigma
#define TILE  8192                   // edges per partition block (long runs -> low write amp)
#define NT4   (N_EDGES / 4)          // int4 count per edge row

// ---------- FAST-PATH workspace layout (bytes) ----------
#define F_CURSOR_OFF 0
#define F_NORM_OFF   3200
#define F_PSUM_OFF   3328
#define F_PSUMSQ_OFF 31488
#define F_FEATS_OFF  59648
#define F_SP4_OFF    3659648
#define F_SLOTS_OFF  5259648
#define F_ZERO_BYTES 3200            // cursor only
#define F_WS_NEED    (5259648ull + (unsigned long long)(NB * CAPB + 1) * 4)

// ---------- FALLBACK workspace layout (round-1 algorithm) ----------
#define B_ACC_OFF    0
#define B_STATS_OFF  4800000
#define B_NORM_OFF   4800144
#define B_FEATS_OFF  4800224
#define B_ZERO_BYTES 4800144

__device__ __forceinline__ void atomAddF(float* p, float v) {
#if defined(__gfx950__) || defined(__gfx942__) || defined(__gfx90a__)
    unsafeAtomicAdd(p, v);
#else
    atomicAdd(p, v);
#endif
}

// ============================================================================
// Shared device helpers
// ============================================================================

__device__ __forceinline__ void eig3_sym(
        float a00, float a01, float a02, float a11, float a12, float a22,
        float& e1, float& e2, float& e3) {
    float p1 = a01 * a01 + a02 * a02 + a12 * a12;
    float qm = (a00 + a11 + a22) * (1.0f / 3.0f);
    float b00 = a00 - qm, b11 = a11 - qm, b22 = a22 - qm;
    float p2 = b00 * b00 + b11 * b11 + b22 * b22 + 2.0f * p1;
    if (p2 <= 1e-24f) {
        e1 = qm; e2 = qm; e3 = qm;
    } else {
        float p = sqrtf(p2 * (1.0f / 6.0f));
        float invp = 1.0f / p;
        float c00 = b00 * invp, c11 = b11 * invp, c22 = b22 * invp;
        float c01 = a01 * invp, c02 = a02 * invp, c12 = a12 * invp;
        float detB = c00 * (c11 * c22 - c12 * c12)
                   - c01 * (c01 * c22 - c12 * c02)
                   + c02 * (c01 * c12 - c11 * c02);
        float r = 0.5f * detB;
        r = fminf(fmaxf(r, -1.0f), 1.0f);
        float phi = acosf(r) * (1.0f / 3.0f);
        e1 = qm + 2.0f * p * cosf(phi);
        e3 = qm + 2.0f * p * cosf(phi + 2.0943951023931953f); // +2pi/3
        e2 = 3.0f * qm - e1 - e3;
    }
}

// sums: n,sumd,sumd2,sx,sy,sz,xx,xy,xz,yy,yz,zz -> 9 features
__device__ __forceinline__ void sums_to_feats(
        const float* s, float qx, float qy, float qz, float* f) {
    float n = s[0];
#pragma unroll
    for (int k = 0; k < 9; ++k) f[k] = 0.0f;
    if (n > 0.0f) {
        float inv = 1.0f / n;
        float Davg = s[1] * inv;
        float Dvar = fmaxf(s[2] * inv - Davg * Davg, 0.0f);
        float cx = s[3] * inv, cy = s[4] * inv, cz = s[5] * inv;
        float a00 = fmaxf(s[6] * inv - cx * cx, 0.0f);
        float a01 = s[7] * inv - cx * cy;
        float a02 = s[8] * inv - cx * cz;
        float a11 = fmaxf(s[9] * inv - cy * cy, 0.0f);
        float a12 = s[10] * inv - cy * cz;
        float a22 = fmaxf(s[11] * inv - cz * cz, 0.0f);
        float e1, e2, e3;
        eig3_sym(a00, a01, a02, a11, a12, a22, e1, e2, e3);
        f[0] = n; f[1] = Davg; f[2] = Dvar;
        f[3] = cx - qx; f[4] = cy - qy; f[5] = cz - qz;
        f[6] = e1; f[7] = e2; f[8] = e3;
    }
}

// ============================================================================
// FAST PATH
// ============================================================================

// TILE=8192, 512 threads, ~72 KB LDS -> 2 blocks/CU; all 391 blocks resident.
// Long per-bucket runs (~10.5 records) halve slots write amplification vs 4096.
__global__ __launch_bounds__(512, 4) void partition_kernel(
        const int* __restrict__ edge,
        const float* __restrict__ sp,
        float4* __restrict__ sp4,
        int* __restrict__ cursor,
        unsigned int* __restrict__ slots) {
    __shared__ unsigned int s_rec[TILE];   // 32 KB: packed records, bucket-sorted
    __shared__ int s_posh[TILE];           // 32 KB: phase A = histogram[NB]; phase B = dest idx
    __shared__ int s_cur[NB];
    __shared__ int s_off[NB];
    __shared__ int s_wsum[8];

    int tid = threadIdx.x;
    int lane = tid & 63, wv = tid >> 6;
    int tileStart = blockIdx.x * TILE;
    int tileCount = N_EDGES - tileStart;
    if (tileCount > TILE) tileCount = TILE;

    // fused sp -> sp4 pad (391 blocks x 512 threads = 200k >= S_NODES)
    {
        int i = blockIdx.x * 512 + tid;
        if (i < S_NODES)
            sp4[i] = make_float4(sp[3 * i], sp[3 * i + 1], sp[3 * i + 2], 0.0f);
    }

    for (int b = tid; b < NB; b += 512) s_posh[b] = 0;
    __syncthreads();

    const int4* eq4 = (const int4*)edge;
    const int4* es4 = (const int4*)(edge + N_EDGES);
    int base4 = blockIdx.x * (TILE / 4);
    int4 q4[4], s4[4];
    bool v[4];
#pragma unroll
    for (int j = 0; j < 4; ++j) {
        int i4 = base4 + tid + j * 512;
        v[j] = i4 < NT4;
        int ic = v[j] ? i4 : 0;
        q4[j] = eq4[ic];
        s4[j] = es4[ic];
        if (v[j]) {
            atomicAdd(&s_posh[q4[j].x >> 7], 1);
            atomicAdd(&s_posh[q4[j].y >> 7], 1);
            atomicAdd(&s_posh[q4[j].z >> 7], 1);
            atomicAdd(&s_posh[q4[j].w >> 7], 1);
        }
    }
    __syncthreads();

    // exclusive prefix of histogram -> s_cur (512 threads x 2 elems >= NB)
    int local[2], tsum = 0;
#pragma unroll
    for (int j = 0; j < 2; ++j) {
        int idx = 2 * tid + j;
        local[j] = (idx < NB) ? s_posh[idx] : 0;
        tsum += local[j];
    }
    int inc = tsum;
#pragma unroll
    for (int off = 1; off < 64; off <<= 1) {
        int t = __shfl_up(inc, off);
        if (lane >= off) inc += t;
    }
    if (lane == 63) s_wsum[wv] = inc;
    __syncthreads();
    int wbase = 0;
    for (int w = 0; w < wv; ++w) wbase += s_wsum[w];
    int run = wbase + inc - tsum;
#pragma unroll
    for (int j = 0; j < 2; ++j) {
        int idx = 2 * tid + j;
        if (idx < NB) s_cur[idx] = run;
        run += local[j];
    }
    __syncthreads();

    // reserve global space per non-empty bucket (dense cursor: L2-resident)
    for (int b = tid; b < NB; b += 512) {
        int c = s_posh[b];
        int base = c ? atomicAdd(&cursor[b], c) : 0;
        s_off[b] = b * CAPB + base - s_cur[b];
    }
    __syncthreads();   // histogram region of s_posh is now dead

    // scatter into bucket-sorted LDS stage, computing global dest on the fly
#pragma unroll
    for (int j = 0; j < 4; ++j) {
        if (v[j]) {
            int qs[4] = { q4[j].x, q4[j].y, q4[j].z, q4[j].w };
            int ss[4] = { s4[j].x, s4[j].y, s4[j].z, s4[j].w };
#pragma unroll
            for (int m = 0; m < 4; ++m) {
                int bkt = qs[m] >> 7;
                int idx = atomicAdd(&s_cur[bkt], 1);
                int gpos = idx + s_off[bkt];
                if (gpos >= (bkt + 1) * CAPB) gpos = NB * CAPB;  // overflow guard
                s_rec[idx] = ((unsigned)(qs[m] & (QPB - 1)) << 17) | (unsigned)ss[m];
                s_posh[idx] = gpos;
            }
        }
    }
    __syncthreads();

    // write-out: bucket-contiguous runs -> mostly coalesced
    for (int i = tid; i < tileCount; i += 512)
        slots[s_posh[i]] = s_rec[i];
}

// Sort-based accumulate (round-1 proven): LDS counting sort, then 4 threads
// per query over contiguous runs, register sums, deterministic combine.
__global__ __launch_bounds__(512) void bucket_kernel(
        const int* __restrict__ cursor,
        const unsigned int* __restrict__ slots,
        const float4* __restrict__ sp4,
        const float* __restrict__ qp,
        float* __restrict__ feats,
        float* __restrict__ psum,
        float* __restrict__ psumsq) {
    __shared__ unsigned int s_sorted[CAPB];   // 18 KB
    __shared__ float qtile[QPB * 3];
    __shared__ int s_cnt[QPB], s_start[QPB], s_cur[QPB];
    __shared__ float s_part[4][QPB][13];      // 26 KB: 12 sums + pad
    __shared__ float s_red1[8][9], s_red2[8][9];

    int tid = threadIdx.x;
    int b = blockIdx.x;
    int cnt = cursor[b];
    if (cnt > CAPB) cnt = CAPB;

    if (tid < QPB) s_cnt[tid] = 0;
    for (int i = tid; i < QPB * 3; i += 512) {
        int g = b * QPB * 3 + i;
        qtile[i] = (g < Q_NODES * 3) ? qp[g] : 0.0f;
    }
    __syncthreads();

    const unsigned int* bslots = slots + b * CAPB;
    // histogram by query-within-bucket (int LDS atomics = native, fast)
    for (int i = tid; i < cnt; i += 512)
        atomicAdd(&s_cnt[bslots[i] >> 17], 1);
    __syncthreads();

    // exclusive scan of 128 counts by wave 0 (2 elements/lane, shfl scan)
    if (tid < 64) {
        int a0 = s_cnt[tid], a1 = s_cnt[64 + tid];
        int i0 = a0, i1 = a1;
#pragma unroll
        for (int off = 1; off < 64; off <<= 1) {
            int t0 = __shfl_up(i0, off); if (tid >= off) i0 += t0;
            int t1 = __shfl_up(i1, off); if (tid >= off) i1 += t1;
        }
        int tot0 = __shfl(i0, 63);
        s_start[tid] = i0 - a0;              s_cur[tid] = i0 - a0;
        s_start[64 + tid] = i1 - a1 + tot0;  s_cur[64 + tid] = i1 - a1 + tot0;
    }
    __syncthreads();

    // counting-sort scatter into LDS
    for (int i = tid; i < cnt; i += 512) {
        unsigned rec = bslots[i];
        int pos = atomicAdd(&s_cur[rec >> 17], 1);
        s_sorted[pos] = rec;
    }
    __syncthreads();

    // accumulate: 4 threads per query, strided over the degree; deterministic
    // 4-way combine afterwards (no float atomics anywhere).
    {
        int q = tid & (QPB - 1);
        int sub = tid >> 7;                  // 0..3
        float qx = qtile[3 * q + 0], qy = qtile[3 * q + 1], qz = qtile[3 * q + 2];
        float s[12];
#pragma unroll
        for (int k = 0; k < 12; ++k) s[k] = 0.0f;
        int st = s_start[q], deg = s_cnt[q];
        for (int j = sub; j < deg; j += 4) {
            unsigned rec = s_sorted[st + j];
            float4 sv = sp4[rec & 0x1FFFF];
            float dx = sv.x - qx, dy = sv.y - qy, dz = sv.z - qz;
            float d2 = dx * dx + dy * dy + dz * dz;
            s[0] += 1.0f;
            s[1] += sqrtf(d2);
            s[2] += d2;
            s[3] += sv.x; s[4] += sv.y; s[5] += sv.z;
            s[6] += sv.x * sv.x; s[7] += sv.x * sv.y; s[8] += sv.x * sv.z;
            s[9] += sv.y * sv.y; s[10] += sv.y * sv.z; s[11] += sv.z * sv.z;
        }
#pragma unroll
        for (int k = 0; k < 12; ++k) s_part[sub][q][k] = s[k];
    }
    __syncthreads();

    // per-query finalize by threads 0..127
    float f[9];
#pragma unroll
    for (int k = 0; k < 9; ++k) f[k] = 0.0f;
    int q = b * QPB + (tid & (QPB - 1));
    if (tid < QPB && q < Q_NODES) {
        float qx = qtile[3 * tid + 0], qy = qtile[3 * tid + 1], qz = qtile[3 * tid + 2];
        float s[12];
#pragma unroll
        for (int k = 0; k < 12; ++k)
            s[k] = ((s_part[0][tid][k] + s_part[1][tid][k])
                  + (s_part[2][tid][k] + s_part[3][tid][k]));
        sums_to_feats(s, qx, qy, qz, f);
#pragma unroll
        for (int k = 0; k < 9; ++k) feats[k * Q_NODES + q] = f[k];  // coalesced per k
    }

    // dataset-wide stats: wave reduce -> LDS -> one partial row per block
    int lane = tid & 63, wv = tid >> 6;
#pragma unroll
    for (int k = 0; k < 9; ++k) {
        float s1 = f[k];
        float s2 = f[k] * f[k];
#pragma unroll
        for (int off = 32; off > 0; off >>= 1) {
            s1 += __shfl_down(s1, off);
            s2 += __shfl_down(s2, off);
        }
        if (lane == 0) { s_red1[wv][k] = s1; s_red2[wv][k] = s2; }
    }
    __syncthreads();
    if (tid < 9) {
        float t1 = 0.0f, t2 = 0.0f;
#pragma unroll
        for (int w = 0; w < 8; ++w) { t1 += s_red1[w][tid]; t2 += s_red2[w][tid]; }
        psum[tid * NB + b]   = t1;
        psumsq[tid * NB + b] = t2;
    }
}

// 9 waves, one per feature column; no barriers.
__global__ __launch_bounds__(576) void stats_reduce_kernel(
        const float* __restrict__ psum,
        const float* __restrict__ psumsq,
        float* __restrict__ norm) {
    int k = threadIdx.x >> 6, lane = threadIdx.x & 63;
    if (k >= 9) return;
    double a1 = 0.0, a2 = 0.0;
    for (int b = lane; b < NB; b += 64) {
        a1 += (double)psum[k * NB + b];
        a2 += (double)psumsq[k * NB + b];
    }
#pragma unroll
    for (int off = 32; off > 0; off >>= 1) {
        a1 += __shfl_down(a1, off);
        a2 += __shfl_down(a2, off);
    }
    if (lane == 0) {
        double S = a1, S2 = a2;
        double mean = S / (double)Q_NODES;
        double var = (S2 - S * S / (double)Q_NODES) / (double)(Q_NODES - 1);
        if (var < 0.0) var = 0.0;
        double sd = sqrt(var);
        if (sd < 1e-6) sd = 1.0;
        norm[k] = (float)mean;
        norm[9 + k] = (float)(1.0 / sd);
    }
}

// ============================================================================
// MLP (round-1 proven): one block per 128-query tile computes BOTH output
// halves. Layer-1 h-tile -> LDS [k][q] once; W2^T half -> LDS [k][o],
// restaged between halves. 8q x 4o regs/thread. 52 KB LDS -> 3 blocks/CU.
// ============================================================================

__global__ __launch_bounds__(256, 3) void mlp_kernel(
        const float* __restrict__ feats,
        const float* __restrict__ norm,
        const float* __restrict__ W1, const float* __restrict__ b1,
        const float* __restrict__ W2, const float* __restrict__ b2,
        float* __restrict__ out) {
    __shared__ float sW1[576];        // [64][9]
    __shared__ float sB1[64];
    __shared__ float sB2[128];
    __shared__ float sNorm[18];
    __shared__ float w2t[64 * 64];    // [k][o within half], restaged per half
    __shared__ float ht[64 * 128];    // [k][q]

    int tid = threadIdx.x;
    int blk_q = blockIdx.x;

    for (int i = tid; i < 576; i += 256) sW1[i] = W1[i];
    if (tid < 64) sB1[tid] = b1[tid];
    if (tid < 128) sB2[tid] = b2[tid];
    if (tid < 18) sNorm[tid] = norm[tid];

    // W2^T staging (half 0): thread owns column o = tid&63, k-chunk of 16.
    {
        int o = tid & 63, kc = (tid >> 6) * 16;
#pragma unroll
        for (int j = 0; j < 16; ++j) {
            int k = kc + j;
            w2t[k * 64 + o] = W2[o * 64 + k];
        }
    }
    __syncthreads();

    // Layer 1 (once per tile): thread (q = tid&127, half = tid>>7) -> 32 h-rows.
    {
        int q = tid & 127, half = tid >> 7;
        int qg = blk_q * 128 + q;
        int qc = qg < Q_NODES ? qg : Q_NODES - 1;
        float f[9];
#pragma unroll
        for (int k = 0; k < 9; ++k)
            f[k] = (feats[k * Q_NODES + qc] - sNorm[k]) * sNorm[9 + k];
#pragma unroll 4
        for (int j = 0; j < 32; ++j) {
            int ko = half * 32 + j;
            float a = sB1[ko];
#pragma unroll
            for (int kf = 0; kf < 9; ++kf) a = fmaf(f[kf], sW1[ko * 9 + kf], a);
            ht[ko * 128 + q] = fmaxf(a, 0.0f);   // banks: lanes span q -> free
        }
    }
    __syncthreads();

    // Layer 2: two o-halves, thread tile 8q x 4o per half.
    int qt = tid >> 4, ot = tid & 15;
    int q0 = qt * 8, o0 = ot * 4;

#pragma unroll 1
    for (int pass = 0; pass < 2; ++pass) {
        int oh = pass * 64;
        if (pass) {
            __syncthreads();   // all pass-0 w2t reads done
            int o = tid & 63, kc = (tid >> 6) * 16;
#pragma unroll
            for (int j = 0; j < 16; ++j) {
                int k = kc + j;
                w2t[k * 64 + o] = W2[(oh + o) * 64 + k];
            }
            __syncthreads();
        }

        float acc[8][4];
#pragma unroll
        for (int i = 0; i < 8; ++i)
#pragma unroll
            for (int j = 0; j < 4; ++j) acc[i][j] = 0.0f;

#pragma unroll 4
        for (int k = 0; k < 64; ++k) {
            float4 h0 = *(const float4*)&ht[k * 128 + q0];       // broadcast, free
            float4 h1 = *(const float4*)&ht[k * 128 + q0 + 4];
            float4 w  = *(const float4*)&w2t[k * 64 + o0];       // 2-way, free
            float hh[8] = { h0.x, h0.y, h0.z, h0.w, h1.x, h1.y, h1.z, h1.w };
#pragma unroll
            for (int i = 0; i < 8; ++i) {
                acc[i][0] = fmaf(hh[i], w.x, acc[i][0]);
                acc[i][1] = fmaf(hh[i], w.y, acc[i][1]);
                acc[i][2] = fmaf(hh[i], w.z, acc[i][2]);
                acc[i][3] = fmaf(hh[i], w.w, acc[i][3]);
            }
        }

        float4 bb = *(const float4*)&sB2[oh + o0];
#pragma unroll
        for (int i = 0; i < 8; ++i) {
            int qg = blk_q * 128 + q0 + i;
            if (qg < Q_NODES) {
                float4 vv = make_float4(acc[i][0] + bb.x, acc[i][1] + bb.y,
                                        acc[i][2] + bb.z, acc[i][3] + bb.w);
                *(float4*)(out + (size_t)qg * 128 + oh + o0) = vv;
            }
        }
    }
}

// ============================================================================
// FALLBACK PATH (round-1 algorithm, used only if ws_size too small)
// ============================================================================

__global__ __launch_bounds__(256) void edge_kernel(
        const int* __restrict__ edge,
        const float* __restrict__ sp,
        const float* __restrict__ qp,
        float* __restrict__ acc) {
    int e = blockIdx.x * 256 + threadIdx.x;
    if (e >= N_EDGES) return;
    int q = edge[e];
    int s = edge[N_EDGES + e];
    float sx = sp[3 * s + 0], sy = sp[3 * s + 1], sz = sp[3 * s + 2];
    float qx = qp[3 * q + 0], qy = qp[3 * q + 1], qz = qp[3 * q + 2];
    float dx = sx - qx, dy = sy - qy, dz = sz - qz;
    float d2 = dx * dx + dy * dy + dz * dz;
    atomAddF(acc + 0 * Q_NODES + q, 1.0f);
    atomAddF(acc + 1 * Q_NODES + q, sqrtf(d2));
    atomAddF(acc + 2 * Q_NODES + q, d2);
    atomAddF(acc + 3 * Q_NODES + q, sx);
    atomAddF(acc + 4 * Q_NODES + q, sy);
    atomAddF(acc + 5 * Q_NODES + q, sz);
    atomAddF(acc + 6 * Q_NODES + q, sx * sx);
    atomAddF(acc + 7 * Q_NODES + q, sx * sy);
    atomAddF(acc + 8 * Q_NODES + q, sx * sz);
    atomAddF(acc + 9 * Q_NODES + q, sy * sy);
    atomAddF(acc + 10 * Q_NODES + q, sy * sz);
    atomAddF(acc + 11 * Q_NODES + q, sz * sz);
}

__global__ __launch_bounds__(256) void finalize_kernel(
        const float* __restrict__ acc,
        const float* __restrict__ qp,
        float* __restrict__ feats,
        double* __restrict__ stats) {
    int q = blockIdx.x * 256 + threadIdx.x;
    float f[9];
#pragma unroll
    for (int k = 0; k < 9; ++k) f[k] = 0.0f;
    if (q < Q_NODES) {
        float s[12];
#pragma unroll
        for (int k = 0; k < 12; ++k) s[k] = acc[k * Q_NODES + q];
        float qx = qp[3 * q + 0], qy = qp[3 * q + 1], qz = qp[3 * q + 2];
        sums_to_feats(s, qx, qy, qz, f);
#pragma unroll
        for (int k = 0; k < 9; ++k) feats[k * Q_NODES + q] = f[k];
    }
    int lane = threadIdx.x & 63;
#pragma unroll
    for (int k = 0; k < 9; ++k) {
        float s1 = f[k];
        float s2 = f[k] * f[k];
#pragma unroll
        for (int off = 32; off > 0; off >>= 1) {
            s1 += __shfl_down(s1, off);
            s2 += __shfl_down(s2, off);
        }
        if (lane == 0) {
            atomicAdd(&stats[k], (double)s1);
            atomicAdd(&stats[9 + k], (double)s2);
        }
    }
}

__global__ void stats_kernel(const double* __restrict__ stats,
                             float* __restrict__ norm) {
    int k = threadIdx.x;
    if (k < 9) {
        double S = stats[k], S2 = stats[9 + k];
        double mean = S / (double)Q_NODES;
        double var = (S2 - S * S / (double)Q_NODES) / (double)(Q_NODES - 1);
        if (var < 0.0) var = 0.0;
        double sd = sqrt(var);
        if (sd < 1e-6) sd = 1.0;
        norm[k] = (float)mean;
        norm[9 + k] = (float)(1.0 / sd);
    }
}

// ============================================================================

extern "C" void kernel_launch(void* const* d_in, const int* in_sizes, int n_in,
                              void* d_out, int out_size, void* d_ws, size_t ws_size,
                              hipStream_t stream) {
    const float* sp   = (const float*)d_in[0];
    const float* qp   = (const float*)d_in[1];
    const int*   edge = (const int*)d_in[2];
    const float* W1   = (const float*)d_in[3];
    const float* b1   = (const float*)d_in[4];
    const float* W2   = (const float*)d_in[5];
    const float* b2   = (const float*)d_in[6];
    float* out = (float*)d_out;
    char* ws = (char*)d_ws;

    if (ws_size >= F_WS_NEED) {
        int*          cursor = (int*)(ws + F_CURSOR_OFF);
        float*        norm   = (float*)(ws + F_NORM_OFF);
        float*        psum   = (float*)(ws + F_PSUM_OFF);
        float*        psumsq = (float*)(ws + F_PSUMSQ_OFF);
        float*        feats  = (float*)(ws + F_FEATS_OFF);
        float4*       sp4    = (float4*)(ws + F_SP4_OFF);
        unsigned int* slots  = (unsigned int*)(ws + F_SLOTS_OFF);

        hipMemsetAsync(ws, 0, F_ZERO_BYTES, stream);
        partition_kernel<<<(N_EDGES + TILE - 1) / TILE, 512, 0, stream>>>(
            edge, sp, sp4, cursor, slots);
        bucket_kernel<<<NB, 512, 0, stream>>>(
            cursor, slots, sp4, qp, feats, psum, psumsq);
        stats_reduce_kernel<<<1, 576, 0, stream>>>(psum, psumsq, norm);
        mlp_kernel<<<NB, 256, 0, stream>>>(feats, norm, W1, b1, W2, b2, out);
    } else {
        float*  acc   = (float*)(ws + B_ACC_OFF);
        double* stats = (double*)(ws + B_STATS_OFF);
        float*  norm  = (float*)(ws + B_NORM_OFF);
        float*  feats = (float*)(ws + B_FEATS_OFF);

        hipMemsetAsync(ws, 0, B_ZERO_BYTES, stream);
        edge_kernel<<<N_EDGES / 256, 256, 0, stream>>>(edge, sp, qp, acc);
        finalize_kernel<<<(Q_NODES + 255) / 256, 256, 0, stream>>>(acc, qp, feats, stats);
        stats_kernel<<<1, 64, 0, stream>>>(stats, norm);
        mlp_kernel<<<NB, 256, 0, stream>>>(feats, norm, W1, b1, W2, b2, out);
    }
}